// Round 3
// baseline (198.782 us; speedup 1.0000x reference)
//
#include <hip/hip_runtime.h>
#include <math.h>

// Network_22892175688023 — round 13: persistent k_rest with grid barriers. 2 stages.
//   K1 k_prep_enc1 : E-planes + Xs frags + enc L1 VALU + zero barriers (576 blk) [unchanged math]
//   K2 k_rest      : 256 blk x 256 thr, 1 block/CU (co-residency guaranteed):
//                    P1 enc2 (blocks 0-63) -> gbar
//                    P2 gate (redundant per msub, bit-identical) + gen1+comb1 (split-N) -> gbar
//                    P3 gen2+comb2 (split-N) -> gbar
//                    P4 gen3 (g==0 blocks, 4 waves x 2 experts) + reduce -> out
//   All accumulation orders verbatim from R12 -> same numerics (absmax 0.00390625).
//   Rationale: 5-launch chain cost ~launch+drain per stage at 1 wave/SIMD; barriers
//   replace 3 launch boundaries; bc stays in LDS; counters become per-kernel visible.

#define DIN 103
#define NE  8
#define HH  256
#define DOUT 51
#define EPSBN 1e-5f

typedef __attribute__((ext_vector_type(8))) short bf16x8;
typedef __attribute__((ext_vector_type(4))) float f32x4;
typedef __attribute__((ext_vector_type(8))) unsigned short us8;
typedef unsigned short ushort_t;

__device__ __forceinline__ float eluf(float v) { return v > 0.f ? v : (expf(v) - 1.f); }
__device__ __forceinline__ unsigned short bf16h(float f) {
  unsigned u = __float_as_uint(f);
  u += 0x7FFFu + ((u >> 16) & 1u);
  return (unsigned short)(u >> 16);
}
__device__ __forceinline__ float bf16f(unsigned short h) { return __uint_as_float(((unsigned)h) << 16); }
__device__ __forceinline__ void split_bf16(float v, unsigned short& h, unsigned short& l) {
  h = bf16h(v);
  l = bf16h(v - bf16f(h));
}
#define MFMA __builtin_amdgcn_mfma_f32_16x16x32_bf16

// ---- ws layout (float offsets) ----
#define O_SLOTS1 0        // [64][128]
#define O_SLOTS2 8192     // [64][64]
#define O_H1RAW  20480    // [1024][64]
#define O_H2RAW  86016    // [1024][32]
#define O_XSH    118784   // [64 msub][4 kc][512] sh
#define O_XSL    184320
#define O_E1H    258048   // [8 e][16 ns][4 kc][512] sh
#define O_E1L    389120
#define O_E2H    520192   // [8 e][16 ns][8 kc][512] sh  (hi only)
#define O_E3H    782336   // [8 e][4 ns][8 kc][512] sh   (hi only)
#define O_A1H    847872   // [64 m][8 kc][512] sh
#define O_A1L    978944
#define O_A2H    1110016
#define O_A2L    1241088
#define O_BAR    1372160  // 3 unsigned barrier counters (zeroed by k_prep_enc1)

// device-scope counting barrier; each counter used exactly once per launch.
__device__ __forceinline__ void gbar(unsigned* c) {
  __syncthreads();
  if (threadIdx.x == 0) {
    __threadfence();
    atomicAdd(c, 1u);
    while (atomicAdd(c, 0u) < 256u) __builtin_amdgcn_s_sleep(2);
    __threadfence();
  }
  __syncthreads();
}

// ================= K1: prep planes + Xs frags + enc L1 (VALU) =================
// blocks: E2 0..255 | E1 256..383 | E3 384..447 | Xs 448..511 | enc1 512..575
__global__ __launch_bounds__(256) void k_prep_enc1(
    const float* __restrict__ x, const float* __restrict__ w1, const float* __restrict__ b1,
    const float* __restrict__ ew1, const float* __restrict__ ew2, const float* __restrict__ ew3,
    float* __restrict__ ws) {
  __shared__ union {
    float tile[32][65];
    float xt[16][104];
    struct { float w1L[64 * DIN]; float xr[16][104]; float hb[16][64]; } e1;
  } sm;
  int bk = blockIdx.x, t = threadIdx.x;
  int l2 = t & 63, c = l2 & 15, q = l2 >> 4;
  if (bk == 0 && t < 4) ((unsigned*)(ws + O_BAR))[t] = 0u;   // reset grid barriers

  if (bk < 256) {          // ---- E2: K=256, N=256, hi only ----
    int nh = bk & 3, kc = (bk >> 2) & 7, e = bk >> 5;
    int k0 = kc * 32, n0 = nh * 64;
#pragma unroll
    for (int i = 0; i < 8; ++i) {
      int kl = (t >> 6) + i * 4;
      sm.tile[kl][t & 63] = ew2[((size_t)e * HH + k0 + kl) * HH + n0 + (t & 63)];
    }
    __syncthreads();
    int nsl = t >> 6;
    us8 H8;
#pragma unroll
    for (int j = 0; j < 8; ++j) H8[j] = bf16h(sm.tile[q * 8 + j][nsl * 16 + c]);
    size_t dst = (((size_t)(e * 16 + nh * 4 + nsl)) * 8 + kc) * 512 + l2 * 8;
    *(us8*)((ushort_t*)(ws + O_E2H) + dst) = H8;
  } else if (bk < 384) {   // ---- E1: K=103->128, N=256, hi+lo ----
    int b2 = bk - 256;
    int nh = b2 & 3, kc = (b2 >> 2) & 3, e = b2 >> 4;
    int k0 = kc * 32, n0 = nh * 64;
#pragma unroll
    for (int i = 0; i < 8; ++i) {
      int kl = (t >> 6) + i * 4;
      int k = k0 + kl;
      sm.tile[kl][t & 63] = (k < DIN) ? ew1[((size_t)e * DIN + k) * HH + n0 + (t & 63)] : 0.f;
    }
    __syncthreads();
    int nsl = t >> 6;
    us8 H8, L8;
#pragma unroll
    for (int j = 0; j < 8; ++j) {
      unsigned short h, lo; split_bf16(sm.tile[q * 8 + j][nsl * 16 + c], h, lo);
      H8[j] = h; L8[j] = lo;
    }
    size_t dst = (((size_t)(e * 16 + nh * 4 + nsl)) * 4 + kc) * 512 + l2 * 8;
    *(us8*)((ushort_t*)(ws + O_E1H) + dst) = H8;
    *(us8*)((ushort_t*)(ws + O_E1L) + dst) = L8;
  } else if (bk < 448) {   // ---- E3: K=256, N=51->64, hi only ----
    int b2 = bk - 384;
    int kc = b2 & 7, e = b2 >> 3;
    int k0 = kc * 32;
#pragma unroll
    for (int i = 0; i < 8; ++i) {
      int kl = (t >> 6) + i * 4;
      int n = t & 63;
      sm.tile[kl][n] = (n < DOUT) ? ew3[((size_t)e * HH + k0 + kl) * DOUT + n] : 0.f;
    }
    __syncthreads();
    int nsl = t >> 6;
    us8 H8;
#pragma unroll
    for (int j = 0; j < 8; ++j) H8[j] = bf16h(sm.tile[q * 8 + j][nsl * 16 + c]);
    size_t dst = (((size_t)(e * 4 + nsl)) * 8 + kc) * 512 + l2 * 8;
    *(us8*)((ushort_t*)(ws + O_E3H) + dst) = H8;
  } else if (bk < 512) {   // ---- Xs: A-fragments of scaled x, 16 rows/block, hi+lo ----
    int msub = bk - 448;
    for (int i = t; i < 16 * 104; i += 256) {
      int b = i / 104, k = i - b * 104;
      float v = 0.f;
      if (k < DIN) { v = x[(size_t)(msub * 16 + b) * DIN + k]; if (k >= 100) v *= 100.f; }
      sm.xt[b][k] = v;
    }
    __syncthreads();
    int kc = t >> 6;
    int m = c;
    us8 H8, L8;
#pragma unroll
    for (int j = 0; j < 8; ++j) {
      int k = kc * 32 + q * 8 + j;
      float v = (k < 104) ? sm.xt[m][k] : 0.f;
      unsigned short h, lo; split_bf16(v, h, lo);
      H8[j] = h; L8[j] = lo;
    }
    size_t dst = ((size_t)msub * 4 + kc) * 512 + l2 * 8;
    *(us8*)((ushort_t*)(ws + O_XSH) + dst) = H8;
    *(us8*)((ushort_t*)(ws + O_XSL) + dst) = L8;
  } else {                 // ---- enc L1 (VALU): 16 rows/block ----
    float* slots1 = ws + O_SLOTS1;
    float* h1raw  = ws + O_H1RAW;
    int bkl = bk - 512;
    int r0 = bkl * 16;
    for (int i = t; i < 64 * DIN; i += 256) sm.e1.w1L[i] = w1[i];
    for (int i = t; i < 16 * 104; i += 256) {
      int r = i / 104, c2 = i - r * 104;
      float v = 0.f;
      if (c2 < DIN) { v = x[(size_t)(r0 + r) * DIN + c2]; if (c2 >= 100) v *= 100.f; }
      sm.e1.xr[r][c2] = v;
    }
    __syncthreads();
#pragma unroll
    for (int i = 0; i < 4; ++i) {
      int idx = t + i * 256;
      int r = idx >> 6, j = idx & 63;
      float acc = b1[j];
      for (int k = 0; k < DIN; ++k) acc = fmaf(sm.e1.xr[r][k], sm.e1.w1L[j * DIN + k], acc);
      sm.e1.hb[r][j] = acc;
      h1raw[(size_t)(r0 + r) * 64 + j] = acc;
    }
    __syncthreads();
    if (t < 64) {
      float s = 0.f, qq = 0.f;
      for (int r = 0; r < 16; ++r) { float v = sm.e1.hb[r][t]; s += v; qq += v * v; }
      slots1[bkl * 128 + t] = s;
      slots1[bkl * 128 + 64 + t] = qq;
    }
  }
}

// ================= K2: k_rest — enc2 | gate+gen1 | gen2 | gen3, grid-barriered =================
__global__ __launch_bounds__(256) void k_rest(
    const float* __restrict__ gamma1, const float* __restrict__ beta1,
    const float* __restrict__ w2, const float* __restrict__ b2,
    const float* __restrict__ gamma2, const float* __restrict__ beta2,
    const float* __restrict__ gw1, const float* __restrict__ gb1,
    const float* __restrict__ gw2, const float* __restrict__ gb2,
    const float* __restrict__ gw3, const float* __restrict__ gb3,
    const float* __restrict__ eb1, const float* __restrict__ eb2,
    const float* __restrict__ eb3,
    float* __restrict__ ws, float* __restrict__ out) {
  __shared__ union {
    struct { float w2T[64 * 33]; float red[128]; float sc1[64], sh1[64];
             float h1b[16][64]; float hb2[16][32]; } enc2;
    struct { float gw1L[64 * 33]; float gw2L[64 * 65]; float gw3L[8 * 65];
             float gb1L[64], gb2L[64], gb3L[8];
             float red2[64], sc2[32], sh2[32];
             float lat[16][32]; float g1[16][64], g2[16][64]; } gate;
    struct { float hT[64][17]; float ebs[512]; } comb;
    struct { float p3s[8][16][64]; float eb3L[8][64]; } g3;
  } U;
  __shared__ float bcL[16][8];                    // persists P2 -> P4

  const int blk = blockIdx.x, t = threadIdx.x;
  const int m = blk >> 2, g = blk & 3;
  const int wv = t >> 6, l = t & 63, c = l & 15, quad = l >> 4;
  const int R0 = m * 16;
  unsigned* bar = (unsigned*)(ws + O_BAR);
  const ushort_t* XsH = (const ushort_t*)(ws + O_XSH);
  const ushort_t* XsL = (const ushort_t*)(ws + O_XSL);
  const ushort_t* E1H = (const ushort_t*)(ws + O_E1H);
  const ushort_t* E1L = (const ushort_t*)(ws + O_E1L);
  const ushort_t* E2H = (const ushort_t*)(ws + O_E2H);
  const ushort_t* E3H = (const ushort_t*)(ws + O_E3H);

  // ---------- P1: enc2 (blocks 0..63, msub = blk) ----------
  if (blk < 64) {
    float* slots1 = ws + O_SLOTS1;
    float* slots2 = ws + O_SLOTS2;
    float* h1raw  = ws + O_H1RAW;
    float* h2raw  = ws + O_H2RAW;
    const int R0e = blk * 16;
    for (int i = t; i < 2048; i += 256) { int j = i >> 6, k = i & 63; U.enc2.w2T[k * 33 + j] = w2[i]; }
    if (t < 128) {
      float s = 0.f;
      for (int b = 0; b < 64; ++b) s += slots1[b * 128 + t];
      U.enc2.red[t] = s;
    }
    __syncthreads();
    if (t < 64) {
      float mm = U.enc2.red[t] * (1.f / 1024.f);
      float v = U.enc2.red[64 + t] * (1.f / 1024.f) - mm * mm;
      float sc = gamma1[t] * rsqrtf(v + EPSBN);
      U.enc2.sc1[t] = sc; U.enc2.sh1[t] = beta1[t] - mm * sc;
    }
    __syncthreads();
#pragma unroll
    for (int i = 0; i < 4; ++i) {
      int idx = t + i * 256;
      int r = idx >> 6, k = idx & 63;
      U.enc2.h1b[r][k] = fmaxf(fmaf(h1raw[(size_t)(R0e + r) * 64 + k], U.enc2.sc1[k], U.enc2.sh1[k]), 0.f);
    }
    __syncthreads();
#pragma unroll
    for (int i = 0; i < 2; ++i) {
      int o = t + i * 256;
      int r = o >> 5, j = o & 31;
      float acc = b2[j];
      for (int k = 0; k < 64; ++k) acc = fmaf(U.enc2.h1b[r][k], U.enc2.w2T[k * 33 + j], acc);
      U.enc2.hb2[r][j] = acc;
      h2raw[(size_t)(R0e + r) * 32 + j] = acc;
    }
    __syncthreads();
    if (t < 32) {
      float s = 0.f, q = 0.f;
      for (int r = 0; r < 16; ++r) { float v = U.enc2.hb2[r][t]; s += v; q += v * v; }
      slots2[blk * 64 + t] = s;
      slots2[blk * 64 + 32 + t] = q;
    }
  }
  gbar(bar + 0);

  // ---------- P2: gate (redundant per msub; bit-identical) + gen1+comb1 ----------
  {
    const float* slots2 = ws + O_SLOTS2;
    const float* h2raw  = ws + O_H2RAW;
    // early A-fragment loads (hide L2/L3 latency under the gate)
    bf16x8 a1h[4], a1l[4];
#pragma unroll
    for (int kc = 0; kc < 4; ++kc) {
      a1h[kc] = *(const bf16x8*)(XsH + ((size_t)m * 4 + kc) * 512 + l * 8);
      a1l[kc] = *(const bf16x8*)(XsL + ((size_t)m * 4 + kc) * 512 + l * 8);
    }
    for (int i = t; i < 2048; i += 256) { int j = i >> 5, k = i & 31; U.gate.gw1L[j * 33 + k] = gw1[i]; }
    for (int i = t; i < 4096; i += 256) { int j = i >> 6, k = i & 63; U.gate.gw2L[j * 65 + k] = gw2[i]; }
    for (int i = t; i < 512; i += 256) { int j = i >> 6, k = i & 63; U.gate.gw3L[j * 65 + k] = gw3[i]; }
    if (t < 64) { U.gate.gb1L[t] = gb1[t]; U.gate.gb2L[t] = gb2[t]; }
    if (t < 8) U.gate.gb3L[t] = gb3[t];
    if (t < 64) {
      float s = 0.f;
      for (int b = 0; b < 64; ++b) s += slots2[b * 64 + t];
      U.gate.red2[t] = s;
    }
    __syncthreads();
    if (t < 32) {
      float mm = U.gate.red2[t] * (1.f / 1024.f);
      float v = U.gate.red2[32 + t] * (1.f / 1024.f) - mm * mm;
      float sc = gamma2[t] * rsqrtf(v + EPSBN);
      U.gate.sc2[t] = sc; U.gate.sh2[t] = beta2[t] - mm * sc;
    }
    __syncthreads();
#pragma unroll
    for (int i = 0; i < 2; ++i) {
      int idx = t + i * 256;
      int r = idx >> 5, cc = idx & 31;
      U.gate.lat[r][cc] = fmaxf(fmaf(h2raw[(size_t)(R0 + r) * 32 + cc], U.gate.sc2[cc], U.gate.sh2[cc]), 0.f);
    }
    __syncthreads();
#pragma unroll
    for (int rr = 0; rr < 4; ++rr) {
      int r = wv * 4 + rr;
      float a1 = U.gate.gb1L[l];
      for (int k = 0; k < 32; ++k) a1 = fmaf(U.gate.gw1L[l * 33 + k], U.gate.lat[r][k], a1);
      U.gate.g1[r][l] = eluf(a1);
    }
    __syncthreads();
#pragma unroll
    for (int rr = 0; rr < 4; ++rr) {
      int r = wv * 4 + rr;
      float a2 = U.gate.gb2L[l];
      for (int k = 0; k < 64; ++k) a2 = fmaf(U.gate.gw2L[l * 65 + k], U.gate.g1[r][k], a2);
      U.gate.g2[r][l] = eluf(a2);
    }
    __syncthreads();
#pragma unroll
    for (int rr = 0; rr < 4; ++rr) {
      int r = wv * 4 + rr;
      if (l < 8) {
        float a3 = U.gate.gb3L[l];
        for (int k = 0; k < 64; ++k) a3 = fmaf(U.gate.gw3L[l * 65 + k], U.gate.g2[r][k], a3);
        float mx = a3;
        mx = fmaxf(mx, __shfl_xor(mx, 1));
        mx = fmaxf(mx, __shfl_xor(mx, 2));
        mx = fmaxf(mx, __shfl_xor(mx, 4));
        float p = expf(a3 - mx);
        float sp = p;
        sp += __shfl_xor(sp, 1); sp += __shfl_xor(sp, 2); sp += __shfl_xor(sp, 4);
        bcL[r][l] = p / sp;
      }
    }
    __syncthreads();   // gate done; union reused below

    // gen1 + comb1 for cols [g*64, g*64+64)
    for (int i = t; i < 512; i += 256) U.comb.ebs[i] = eb1[(i >> 6) * HH + g * 64 + (i & 63)];
    __syncthreads();
    const int ns = g * 4 + wv;
    f32x4 blend = {};
#pragma unroll
    for (int e = 0; e < NE; ++e) {
      float bcv[4];
#pragma unroll
      for (int r = 0; r < 4; ++r) bcv[r] = bcL[quad * 4 + r][e];
      f32x4 acc = {};
#pragma unroll
      for (int kc = 0; kc < 4; ++kc) {
        size_t bo = (((size_t)(e * 16 + ns)) * 4 + kc) * 512 + l * 8;
        bf16x8 bh = *(const bf16x8*)(E1H + bo);
        bf16x8 bl = *(const bf16x8*)(E1L + bo);
        acc = MFMA(a1h[kc], bh, acc, 0, 0, 0);
        acc = MFMA(a1l[kc], bh, acc, 0, 0, 0);
        acc = MFMA(a1h[kc], bl, acc, 0, 0, 0);
      }
      float ebv = U.comb.ebs[e * 64 + wv * 16 + c];
#pragma unroll
      for (int r = 0; r < 4; ++r) blend[r] = fmaf(bcv[r], acc[r] + ebv, blend[r]);
    }
#pragma unroll
    for (int r = 0; r < 4; ++r) U.comb.hT[wv * 16 + c][quad * 4 + r] = eluf(blend[r]);
    __syncthreads();
    if (t < 128) {   // repack 64 cols -> A1 fragment chunks kc = 2g, 2g+1
      int kcl = t >> 6, l2 = t & 63, row = l2 & 15, k0l = kcl * 32 + (l2 >> 4) * 8;
      us8 H, L;
#pragma unroll
      for (int j = 0; j < 8; ++j) {
        unsigned short h, lo; split_bf16(U.comb.hT[k0l + j][row], h, lo);
        H[j] = h; L[j] = lo;
      }
      size_t dst = ((size_t)m * 8 + g * 2 + kcl) * 512 + l2 * 8;
      *(us8*)((ushort_t*)(ws + O_A1H) + dst) = H;
      *(us8*)((ushort_t*)(ws + O_A1L) + dst) = L;
    }
  }
  gbar(bar + 1);

  // ---------- P3: gen2 + comb2 for cols [g*64, g*64+64) ----------
  {
    const ushort_t* A1H = (const ushort_t*)(ws + O_A1H);
    const ushort_t* A1L = (const ushort_t*)(ws + O_A1L);
    for (int i = t; i < 512; i += 256) U.comb.ebs[i] = eb2[(i >> 6) * HH + g * 64 + (i & 63)];
    bf16x8 ah[8], al[8];
#pragma unroll
    for (int kc = 0; kc < 8; ++kc) {
      ah[kc] = *(const bf16x8*)(A1H + ((size_t)m * 8 + kc) * 512 + l * 8);
      al[kc] = *(const bf16x8*)(A1L + ((size_t)m * 8 + kc) * 512 + l * 8);
    }
    __syncthreads();
    const int ns = g * 4 + wv;
    f32x4 blend = {};
#pragma unroll
    for (int e = 0; e < NE; ++e) {
      float bcv[4];
#pragma unroll
      for (int r = 0; r < 4; ++r) bcv[r] = bcL[quad * 4 + r][e];
      f32x4 acc = {};
#pragma unroll
      for (int kc = 0; kc < 8; ++kc) {
        size_t bo = (((size_t)(e * 16 + ns)) * 8 + kc) * 512 + l * 8;
        bf16x8 bh = *(const bf16x8*)(E2H + bo);
        acc = MFMA(ah[kc], bh, acc, 0, 0, 0);
        acc = MFMA(al[kc], bh, acc, 0, 0, 0);
      }
      float ebv = U.comb.ebs[e * 64 + wv * 16 + c];
#pragma unroll
      for (int r = 0; r < 4; ++r) blend[r] = fmaf(bcv[r], acc[r] + ebv, blend[r]);
    }
#pragma unroll
    for (int r = 0; r < 4; ++r) U.comb.hT[wv * 16 + c][quad * 4 + r] = eluf(blend[r]);
    __syncthreads();
    if (t < 128) {
      int kcl = t >> 6, l2 = t & 63, row = l2 & 15, k0l = kcl * 32 + (l2 >> 4) * 8;
      us8 H, L;
#pragma unroll
      for (int j = 0; j < 8; ++j) {
        unsigned short h, lo; split_bf16(U.comb.hT[k0l + j][row], h, lo);
        H[j] = h; L[j] = lo;
      }
      size_t dst = ((size_t)m * 8 + g * 2 + kcl) * 512 + l2 * 8;
      *(us8*)((ushort_t*)(ws + O_A2H) + dst) = H;
      *(us8*)((ushort_t*)(ws + O_A2L) + dst) = L;
    }
  }
  gbar(bar + 2);

  // ---------- P4: gen3 (g==0 blocks; 4 waves x 2 experts) + reduce -> out ----------
  if (g == 0) {
    const ushort_t* A2H = (const ushort_t*)(ws + O_A2H);
    const ushort_t* A2L = (const ushort_t*)(ws + O_A2L);
    for (int i = t; i < 512; i += 256) {
      int e2 = i >> 6, n = i & 63;
      U.g3.eb3L[e2][n] = (n < DOUT) ? eb3[e2 * DOUT + n] : 0.f;
    }
    bf16x8 ah[8], al[8];
#pragma unroll
    for (int kc = 0; kc < 8; ++kc) {
      ah[kc] = *(const bf16x8*)(A2H + ((size_t)m * 8 + kc) * 512 + l * 8);
      al[kc] = *(const bf16x8*)(A2L + ((size_t)m * 8 + kc) * 512 + l * 8);
    }
#pragma unroll
    for (int ee = 0; ee < 2; ++ee) {
      const int e = wv + ee * 4;
      f32x4 acc[4] = {};
#pragma unroll
      for (int kc = 0; kc < 8; ++kc) {
#pragma unroll
        for (int nsi = 0; nsi < 4; ++nsi) {
          size_t bo = (((size_t)(e * 4 + nsi)) * 8 + kc) * 512 + l * 8;
          bf16x8 bh = *(const bf16x8*)(E3H + bo);
          acc[nsi] = MFMA(ah[kc], bh, acc[nsi], 0, 0, 0);
          acc[nsi] = MFMA(al[kc], bh, acc[nsi], 0, 0, 0);
        }
      }
#pragma unroll
      for (int nsi = 0; nsi < 4; ++nsi)
#pragma unroll
        for (int r = 0; r < 4; ++r)
          U.g3.p3s[e][quad * 4 + r][nsi * 16 + c] = acc[nsi][r];
    }
    __syncthreads();
#pragma unroll
    for (int i = 0; i < 4; ++i) {
      int idx = t + i * 256;             // 1024 outputs: [16 rows][64 cols]
      int row = idx >> 6, col = idx & 63;
      float s = 0.f;
#pragma unroll
      for (int e2 = 0; e2 < 8; ++e2)
        s = fmaf(bcL[row][e2], U.g3.p3s[e2][row][col] + U.g3.eb3L[e2][col], s);
      if (col < DOUT) out[(size_t)(R0 + row) * DOUT + col] = s;
    }
  }
}

extern "C" void kernel_launch(void* const* d_in, const int* in_sizes, int n_in,
                              void* d_out, int out_size, void* d_ws, size_t ws_size,
                              hipStream_t stream) {
  const float* x      = (const float*)d_in[0];
  const float* w1     = (const float*)d_in[1];
  const float* b1     = (const float*)d_in[2];
  const float* gamma1 = (const float*)d_in[3];
  const float* beta1  = (const float*)d_in[4];
  const float* w2     = (const float*)d_in[5];
  const float* b2     = (const float*)d_in[6];
  const float* gamma2 = (const float*)d_in[7];
  const float* beta2  = (const float*)d_in[8];
  const float* gw1    = (const float*)d_in[9];
  const float* gb1    = (const float*)d_in[10];
  const float* gw2    = (const float*)d_in[11];
  const float* gb2    = (const float*)d_in[12];
  const float* gw3    = (const float*)d_in[13];
  const float* gb3    = (const float*)d_in[14];
  const float* ew1    = (const float*)d_in[15];
  const float* eb1    = (const float*)d_in[16];
  const float* ew2    = (const float*)d_in[17];
  const float* eb2    = (const float*)d_in[18];
  const float* ew3    = (const float*)d_in[19];
  const float* eb3    = (const float*)d_in[20];
  float* wsf  = (float*)d_ws;
  float* outp = (float*)d_out;

  k_prep_enc1<<<576, 256, 0, stream>>>(x, w1, b1, ew1, ew2, ew3, wsf);
  k_rest<<<256, 256, 0, stream>>>(gamma1, beta1, w2, b2, gamma2, beta2,
                                  gw1, gb1, gw2, gb2, gw3, gb3,
                                  eb1, eb2, eb3, wsf, outp);
}

// Round 4
// 183.830 us; speedup vs baseline: 1.0813x; 1.0813x over previous
//
#include <hip/hip_runtime.h>
#include <math.h>

// Network_22892175688023 — round 14: persistent k_rest, load-spin barrier. 2 stages.
//   K1 k_prep_enc1 : E-planes + Xs frags + enc L1 VALU + zero barriers (576 blk) [unchanged]
//   K2 k_rest      : 256 blk x 256 thr (1 block/CU):
//                    P1 enc2 (blocks 0-63; blocks 64+ preload gate LDS) -> gbar
//                    P2 gate (redundant per msub, bit-identical) + gen1+comb1 (split-N) -> gbar
//                    P3 gen2+comb2 (split-N) -> gbar
//                    P4 gen3 (g==0 blocks, 4 waves x 2 experts) + reduce -> out
//   R13 post-mortem: spin was atomicAdd RMW -> serialized poll turns ~19us apart;
//   barrier exit cost ~60us total. Fix: RELEASE fetch_add arrival + ACQUIRE load spin.
//   All compute bodies verbatim from R13 -> same numerics (absmax 0.00390625).

#define DIN 103
#define NE  8
#define HH  256
#define DOUT 51
#define EPSBN 1e-5f

typedef __attribute__((ext_vector_type(8))) short bf16x8;
typedef __attribute__((ext_vector_type(4))) float f32x4;
typedef __attribute__((ext_vector_type(8))) unsigned short us8;
typedef unsigned short ushort_t;

__device__ __forceinline__ float eluf(float v) { return v > 0.f ? v : (expf(v) - 1.f); }
__device__ __forceinline__ unsigned short bf16h(float f) {
  unsigned u = __float_as_uint(f);
  u += 0x7FFFu + ((u >> 16) & 1u);
  return (unsigned short)(u >> 16);
}
__device__ __forceinline__ float bf16f(unsigned short h) { return __uint_as_float(((unsigned)h) << 16); }
__device__ __forceinline__ void split_bf16(float v, unsigned short& h, unsigned short& l) {
  h = bf16h(v);
  l = bf16h(v - bf16f(h));
}
#define MFMA __builtin_amdgcn_mfma_f32_16x16x32_bf16

// ---- ws layout (float offsets) ----
#define O_SLOTS1 0        // [64][128]
#define O_SLOTS2 8192     // [64][64]
#define O_H1RAW  20480    // [1024][64]
#define O_H2RAW  86016    // [1024][32]
#define O_XSH    118784   // [64 msub][4 kc][512] sh
#define O_XSL    184320
#define O_E1H    258048   // [8 e][16 ns][4 kc][512] sh
#define O_E1L    389120
#define O_E2H    520192   // [8 e][16 ns][8 kc][512] sh  (hi only)
#define O_E3H    782336   // [8 e][4 ns][8 kc][512] sh   (hi only)
#define O_A1H    847872   // [64 m][8 kc][512] sh
#define O_A1L    978944
#define O_A2H    1110016
#define O_A2L    1241088
#define O_BAR    1372160  // 3 unsigned barrier counters (zeroed by k_prep_enc1)

// device-scope counting barrier; each counter used exactly once per launch.
// Arrival: one RELEASE fetch_add per block. Wait: ACQUIRE *load* spin (no RMW
// contention; read-only polls don't ping-pong ownership).
__device__ __forceinline__ void gbar(unsigned* c) {
  __syncthreads();
  if (threadIdx.x == 0) {
    __hip_atomic_fetch_add(c, 1u, __ATOMIC_RELEASE, __HIP_MEMORY_SCOPE_AGENT);
    while (__hip_atomic_load(c, __ATOMIC_ACQUIRE, __HIP_MEMORY_SCOPE_AGENT) < 256u)
      __builtin_amdgcn_s_sleep(8);
  }
  __syncthreads();
}

// ================= K1: prep planes + Xs frags + enc L1 (VALU) =================
// blocks: E2 0..255 | E1 256..383 | E3 384..447 | Xs 448..511 | enc1 512..575
__global__ __launch_bounds__(256) void k_prep_enc1(
    const float* __restrict__ x, const float* __restrict__ w1, const float* __restrict__ b1,
    const float* __restrict__ ew1, const float* __restrict__ ew2, const float* __restrict__ ew3,
    float* __restrict__ ws) {
  __shared__ union {
    float tile[32][65];
    float xt[16][104];
    struct { float w1L[64 * DIN]; float xr[16][104]; float hb[16][64]; } e1;
  } sm;
  int bk = blockIdx.x, t = threadIdx.x;
  int l2 = t & 63, c = l2 & 15, q = l2 >> 4;
  if (bk == 0 && t < 4) ((unsigned*)(ws + O_BAR))[t] = 0u;   // reset grid barriers

  if (bk < 256) {          // ---- E2: K=256, N=256, hi only ----
    int nh = bk & 3, kc = (bk >> 2) & 7, e = bk >> 5;
    int k0 = kc * 32, n0 = nh * 64;
#pragma unroll
    for (int i = 0; i < 8; ++i) {
      int kl = (t >> 6) + i * 4;
      sm.tile[kl][t & 63] = ew2[((size_t)e * HH + k0 + kl) * HH + n0 + (t & 63)];
    }
    __syncthreads();
    int nsl = t >> 6;
    us8 H8;
#pragma unroll
    for (int j = 0; j < 8; ++j) H8[j] = bf16h(sm.tile[q * 8 + j][nsl * 16 + c]);
    size_t dst = (((size_t)(e * 16 + nh * 4 + nsl)) * 8 + kc) * 512 + l2 * 8;
    *(us8*)((ushort_t*)(ws + O_E2H) + dst) = H8;
  } else if (bk < 384) {   // ---- E1: K=103->128, N=256, hi+lo ----
    int b2 = bk - 256;
    int nh = b2 & 3, kc = (b2 >> 2) & 3, e = b2 >> 4;
    int k0 = kc * 32, n0 = nh * 64;
#pragma unroll
    for (int i = 0; i < 8; ++i) {
      int kl = (t >> 6) + i * 4;
      int k = k0 + kl;
      sm.tile[kl][t & 63] = (k < DIN) ? ew1[((size_t)e * DIN + k) * HH + n0 + (t & 63)] : 0.f;
    }
    __syncthreads();
    int nsl = t >> 6;
    us8 H8, L8;
#pragma unroll
    for (int j = 0; j < 8; ++j) {
      unsigned short h, lo; split_bf16(sm.tile[q * 8 + j][nsl * 16 + c], h, lo);
      H8[j] = h; L8[j] = lo;
    }
    size_t dst = (((size_t)(e * 16 + nh * 4 + nsl)) * 4 + kc) * 512 + l2 * 8;
    *(us8*)((ushort_t*)(ws + O_E1H) + dst) = H8;
    *(us8*)((ushort_t*)(ws + O_E1L) + dst) = L8;
  } else if (bk < 448) {   // ---- E3: K=256, N=51->64, hi only ----
    int b2 = bk - 384;
    int kc = b2 & 7, e = b2 >> 3;
    int k0 = kc * 32;
#pragma unroll
    for (int i = 0; i < 8; ++i) {
      int kl = (t >> 6) + i * 4;
      int n = t & 63;
      sm.tile[kl][n] = (n < DOUT) ? ew3[((size_t)e * HH + k0 + kl) * DOUT + n] : 0.f;
    }
    __syncthreads();
    int nsl = t >> 6;
    us8 H8;
#pragma unroll
    for (int j = 0; j < 8; ++j) H8[j] = bf16h(sm.tile[q * 8 + j][nsl * 16 + c]);
    size_t dst = (((size_t)(e * 4 + nsl)) * 8 + kc) * 512 + l2 * 8;
    *(us8*)((ushort_t*)(ws + O_E3H) + dst) = H8;
  } else if (bk < 512) {   // ---- Xs: A-fragments of scaled x, 16 rows/block, hi+lo ----
    int msub = bk - 448;
    for (int i = t; i < 16 * 104; i += 256) {
      int b = i / 104, k = i - b * 104;
      float v = 0.f;
      if (k < DIN) { v = x[(size_t)(msub * 16 + b) * DIN + k]; if (k >= 100) v *= 100.f; }
      sm.xt[b][k] = v;
    }
    __syncthreads();
    int kc = t >> 6;
    int m = c;
    us8 H8, L8;
#pragma unroll
    for (int j = 0; j < 8; ++j) {
      int k = kc * 32 + q * 8 + j;
      float v = (k < 104) ? sm.xt[m][k] : 0.f;
      unsigned short h, lo; split_bf16(v, h, lo);
      H8[j] = h; L8[j] = lo;
    }
    size_t dst = ((size_t)msub * 4 + kc) * 512 + l2 * 8;
    *(us8*)((ushort_t*)(ws + O_XSH) + dst) = H8;
    *(us8*)((ushort_t*)(ws + O_XSL) + dst) = L8;
  } else {                 // ---- enc L1 (VALU): 16 rows/block ----
    float* slots1 = ws + O_SLOTS1;
    float* h1raw  = ws + O_H1RAW;
    int bkl = bk - 512;
    int r0 = bkl * 16;
    for (int i = t; i < 64 * DIN; i += 256) sm.e1.w1L[i] = w1[i];
    for (int i = t; i < 16 * 104; i += 256) {
      int r = i / 104, c2 = i - r * 104;
      float v = 0.f;
      if (c2 < DIN) { v = x[(size_t)(r0 + r) * DIN + c2]; if (c2 >= 100) v *= 100.f; }
      sm.e1.xr[r][c2] = v;
    }
    __syncthreads();
#pragma unroll
    for (int i = 0; i < 4; ++i) {
      int idx = t + i * 256;
      int r = idx >> 6, j = idx & 63;
      float acc = b1[j];
      for (int k = 0; k < DIN; ++k) acc = fmaf(sm.e1.xr[r][k], sm.e1.w1L[j * DIN + k], acc);
      sm.e1.hb[r][j] = acc;
      h1raw[(size_t)(r0 + r) * 64 + j] = acc;
    }
    __syncthreads();
    if (t < 64) {
      float s = 0.f, qq = 0.f;
      for (int r = 0; r < 16; ++r) { float v = sm.e1.hb[r][t]; s += v; qq += v * v; }
      slots1[bkl * 128 + t] = s;
      slots1[bkl * 128 + 64 + t] = qq;
    }
  }
}

// ================= K2: k_rest — enc2 | gate+gen1 | gen2 | gen3, grid-barriered =================
__global__ __launch_bounds__(256) void k_rest(
    const float* __restrict__ gamma1, const float* __restrict__ beta1,
    const float* __restrict__ w2, const float* __restrict__ b2,
    const float* __restrict__ gamma2, const float* __restrict__ beta2,
    const float* __restrict__ gw1, const float* __restrict__ gb1,
    const float* __restrict__ gw2, const float* __restrict__ gb2,
    const float* __restrict__ gw3, const float* __restrict__ gb3,
    const float* __restrict__ eb1, const float* __restrict__ eb2,
    const float* __restrict__ eb3,
    float* __restrict__ ws, float* __restrict__ out) {
  __shared__ union {
    struct { float w2T[64 * 33]; float red[128]; float sc1[64], sh1[64];
             float h1b[16][64]; float hb2[16][32]; } enc2;
    struct { float gw1L[64 * 33]; float gw2L[64 * 65]; float gw3L[8 * 65];
             float gb1L[64], gb2L[64], gb3L[8];
             float red2[64], sc2[32], sh2[32];
             float lat[16][32]; float g1[16][64], g2[16][64]; } gate;
    struct { float hT[64][17]; float ebs[512]; } comb;
    struct { float p3s[8][16][64]; float eb3L[8][64]; } g3;
  } U;
  __shared__ float bcL[16][8];                    // persists P2 -> P4

  const int blk = blockIdx.x, t = threadIdx.x;
  const int m = blk >> 2, g = blk & 3;
  const int wv = t >> 6, l = t & 63, c = l & 15, quad = l >> 4;
  const int R0 = m * 16;
  unsigned* bar = (unsigned*)(ws + O_BAR);
  const ushort_t* XsH = (const ushort_t*)(ws + O_XSH);
  const ushort_t* XsL = (const ushort_t*)(ws + O_XSL);
  const ushort_t* E1H = (const ushort_t*)(ws + O_E1H);
  const ushort_t* E1L = (const ushort_t*)(ws + O_E1L);
  const ushort_t* E2H = (const ushort_t*)(ws + O_E2H);
  const ushort_t* E3H = (const ushort_t*)(ws + O_E3H);

  // early A-fragment loads (produced by K1; independent of P1) — hide L3 latency
  bf16x8 a1h[4], a1l[4];
#pragma unroll
  for (int kc = 0; kc < 4; ++kc) {
    a1h[kc] = *(const bf16x8*)(XsH + ((size_t)m * 4 + kc) * 512 + l * 8);
    a1l[kc] = *(const bf16x8*)(XsL + ((size_t)m * 4 + kc) * 512 + l * 8);
  }

  // ---------- P1: enc2 (blocks 0..63); blocks 64+ preload gate weights ----------
  if (blk < 64) {
    float* slots1 = ws + O_SLOTS1;
    float* slots2 = ws + O_SLOTS2;
    float* h1raw  = ws + O_H1RAW;
    float* h2raw  = ws + O_H2RAW;
    const int R0e = blk * 16;
    for (int i = t; i < 2048; i += 256) { int j = i >> 6, k = i & 63; U.enc2.w2T[k * 33 + j] = w2[i]; }
    if (t < 128) {
      float s = 0.f;
      for (int b = 0; b < 64; ++b) s += slots1[b * 128 + t];
      U.enc2.red[t] = s;
    }
    __syncthreads();
    if (t < 64) {
      float mm = U.enc2.red[t] * (1.f / 1024.f);
      float v = U.enc2.red[64 + t] * (1.f / 1024.f) - mm * mm;
      float sc = gamma1[t] * rsqrtf(v + EPSBN);
      U.enc2.sc1[t] = sc; U.enc2.sh1[t] = beta1[t] - mm * sc;
    }
    __syncthreads();
#pragma unroll
    for (int i = 0; i < 4; ++i) {
      int idx = t + i * 256;
      int r = idx >> 6, k = idx & 63;
      U.enc2.h1b[r][k] = fmaxf(fmaf(h1raw[(size_t)(R0e + r) * 64 + k], U.enc2.sc1[k], U.enc2.sh1[k]), 0.f);
    }
    __syncthreads();
#pragma unroll
    for (int i = 0; i < 2; ++i) {
      int o = t + i * 256;
      int r = o >> 5, j = o & 31;
      float acc = b2[j];
      for (int k = 0; k < 64; ++k) acc = fmaf(U.enc2.h1b[r][k], U.enc2.w2T[k * 33 + j], acc);
      U.enc2.hb2[r][j] = acc;
      h2raw[(size_t)(R0e + r) * 32 + j] = acc;
    }
    __syncthreads();
    if (t < 32) {
      float s = 0.f, q = 0.f;
      for (int r = 0; r < 16; ++r) { float v = U.enc2.hb2[r][t]; s += v; q += v * v; }
      slots2[blk * 64 + t] = s;
      slots2[blk * 64 + 32 + t] = q;
    }
  } else {
    // idle in P1: preload gate weight tiles now (U.enc2 unused in these blocks)
    for (int i = t; i < 2048; i += 256) { int j = i >> 5, k = i & 31; U.gate.gw1L[j * 33 + k] = gw1[i]; }
    for (int i = t; i < 4096; i += 256) { int j = i >> 6, k = i & 63; U.gate.gw2L[j * 65 + k] = gw2[i]; }
    for (int i = t; i < 512; i += 256) { int j = i >> 6, k = i & 63; U.gate.gw3L[j * 65 + k] = gw3[i]; }
    if (t < 64) { U.gate.gb1L[t] = gb1[t]; U.gate.gb2L[t] = gb2[t]; }
    if (t < 8) U.gate.gb3L[t] = gb3[t];
  }
  gbar(bar + 0);

  // ---------- P2: gate (redundant per msub; bit-identical) + gen1+comb1 ----------
  {
    const float* slots2 = ws + O_SLOTS2;
    const float* h2raw  = ws + O_H2RAW;
    if (blk < 64) {   // these blocks ran enc2 in P1; load gate weights now
      for (int i = t; i < 2048; i += 256) { int j = i >> 5, k = i & 31; U.gate.gw1L[j * 33 + k] = gw1[i]; }
      for (int i = t; i < 4096; i += 256) { int j = i >> 6, k = i & 63; U.gate.gw2L[j * 65 + k] = gw2[i]; }
      for (int i = t; i < 512; i += 256) { int j = i >> 6, k = i & 63; U.gate.gw3L[j * 65 + k] = gw3[i]; }
      if (t < 64) { U.gate.gb1L[t] = gb1[t]; U.gate.gb2L[t] = gb2[t]; }
      if (t < 8) U.gate.gb3L[t] = gb3[t];
    }
    if (t < 64) {
      float s = 0.f;
      for (int b = 0; b < 64; ++b) s += slots2[b * 64 + t];
      U.gate.red2[t] = s;
    }
    __syncthreads();
    if (t < 32) {
      float mm = U.gate.red2[t] * (1.f / 1024.f);
      float v = U.gate.red2[32 + t] * (1.f / 1024.f) - mm * mm;
      float sc = gamma2[t] * rsqrtf(v + EPSBN);
      U.gate.sc2[t] = sc; U.gate.sh2[t] = beta2[t] - mm * sc;
    }
    __syncthreads();
#pragma unroll
    for (int i = 0; i < 2; ++i) {
      int idx = t + i * 256;
      int r = idx >> 5, cc = idx & 31;
      U.gate.lat[r][cc] = fmaxf(fmaf(h2raw[(size_t)(R0 + r) * 32 + cc], U.gate.sc2[cc], U.gate.sh2[cc]), 0.f);
    }
    __syncthreads();
#pragma unroll
    for (int rr = 0; rr < 4; ++rr) {
      int r = wv * 4 + rr;
      float a1 = U.gate.gb1L[l];
      for (int k = 0; k < 32; ++k) a1 = fmaf(U.gate.gw1L[l * 33 + k], U.gate.lat[r][k], a1);
      U.gate.g1[r][l] = eluf(a1);
    }
    __syncthreads();
#pragma unroll
    for (int rr = 0; rr < 4; ++rr) {
      int r = wv * 4 + rr;
      float a2 = U.gate.gb2L[l];
      for (int k = 0; k < 64; ++k) a2 = fmaf(U.gate.gw2L[l * 65 + k], U.gate.g1[r][k], a2);
      U.gate.g2[r][l] = eluf(a2);
    }
    __syncthreads();
#pragma unroll
    for (int rr = 0; rr < 4; ++rr) {
      int r = wv * 4 + rr;
      if (l < 8) {
        float a3 = U.gate.gb3L[l];
        for (int k = 0; k < 64; ++k) a3 = fmaf(U.gate.gw3L[l * 65 + k], U.gate.g2[r][k], a3);
        float mx = a3;
        mx = fmaxf(mx, __shfl_xor(mx, 1));
        mx = fmaxf(mx, __shfl_xor(mx, 2));
        mx = fmaxf(mx, __shfl_xor(mx, 4));
        float p = expf(a3 - mx);
        float sp = p;
        sp += __shfl_xor(sp, 1); sp += __shfl_xor(sp, 2); sp += __shfl_xor(sp, 4);
        bcL[r][l] = p / sp;
      }
    }
    __syncthreads();   // gate done; union reused below

    // gen1 + comb1 for cols [g*64, g*64+64)
    for (int i = t; i < 512; i += 256) U.comb.ebs[i] = eb1[(i >> 6) * HH + g * 64 + (i & 63)];
    __syncthreads();
    const int ns = g * 4 + wv;
    f32x4 blend = {};
#pragma unroll
    for (int e = 0; e < NE; ++e) {
      float bcv[4];
#pragma unroll
      for (int r = 0; r < 4; ++r) bcv[r] = bcL[quad * 4 + r][e];
      f32x4 acc = {};
#pragma unroll
      for (int kc = 0; kc < 4; ++kc) {
        size_t bo = (((size_t)(e * 16 + ns)) * 4 + kc) * 512 + l * 8;
        bf16x8 bh = *(const bf16x8*)(E1H + bo);
        bf16x8 bl = *(const bf16x8*)(E1L + bo);
        acc = MFMA(a1h[kc], bh, acc, 0, 0, 0);
        acc = MFMA(a1l[kc], bh, acc, 0, 0, 0);
        acc = MFMA(a1h[kc], bl, acc, 0, 0, 0);
      }
      float ebv = U.comb.ebs[e * 64 + wv * 16 + c];
#pragma unroll
      for (int r = 0; r < 4; ++r) blend[r] = fmaf(bcv[r], acc[r] + ebv, blend[r]);
    }
#pragma unroll
    for (int r = 0; r < 4; ++r) U.comb.hT[wv * 16 + c][quad * 4 + r] = eluf(blend[r]);
    __syncthreads();
    if (t < 128) {   // repack 64 cols -> A1 fragment chunks kc = 2g, 2g+1
      int kcl = t >> 6, l2 = t & 63, row = l2 & 15, k0l = kcl * 32 + (l2 >> 4) * 8;
      us8 H, L;
#pragma unroll
      for (int j = 0; j < 8; ++j) {
        unsigned short h, lo; split_bf16(U.comb.hT[k0l + j][row], h, lo);
        H[j] = h; L[j] = lo;
      }
      size_t dst = ((size_t)m * 8 + g * 2 + kcl) * 512 + l2 * 8;
      *(us8*)((ushort_t*)(ws + O_A1H) + dst) = H;
      *(us8*)((ushort_t*)(ws + O_A1L) + dst) = L;
    }
  }
  gbar(bar + 1);

  // ---------- P3: gen2 + comb2 for cols [g*64, g*64+64) ----------
  {
    const ushort_t* A1H = (const ushort_t*)(ws + O_A1H);
    const ushort_t* A1L = (const ushort_t*)(ws + O_A1L);
    for (int i = t; i < 512; i += 256) U.comb.ebs[i] = eb2[(i >> 6) * HH + g * 64 + (i & 63)];
    bf16x8 ah[8], al[8];
#pragma unroll
    for (int kc = 0; kc < 8; ++kc) {
      ah[kc] = *(const bf16x8*)(A1H + ((size_t)m * 8 + kc) * 512 + l * 8);
      al[kc] = *(const bf16x8*)(A1L + ((size_t)m * 8 + kc) * 512 + l * 8);
    }
    __syncthreads();
    const int ns = g * 4 + wv;
    f32x4 blend = {};
#pragma unroll
    for (int e = 0; e < NE; ++e) {
      float bcv[4];
#pragma unroll
      for (int r = 0; r < 4; ++r) bcv[r] = bcL[quad * 4 + r][e];
      f32x4 acc = {};
#pragma unroll
      for (int kc = 0; kc < 8; ++kc) {
        size_t bo = (((size_t)(e * 16 + ns)) * 8 + kc) * 512 + l * 8;
        bf16x8 bh = *(const bf16x8*)(E2H + bo);
        acc = MFMA(ah[kc], bh, acc, 0, 0, 0);
        acc = MFMA(al[kc], bh, acc, 0, 0, 0);
      }
      float ebv = U.comb.ebs[e * 64 + wv * 16 + c];
#pragma unroll
      for (int r = 0; r < 4; ++r) blend[r] = fmaf(bcv[r], acc[r] + ebv, blend[r]);
    }
#pragma unroll
    for (int r = 0; r < 4; ++r) U.comb.hT[wv * 16 + c][quad * 4 + r] = eluf(blend[r]);
    __syncthreads();
    if (t < 128) {
      int kcl = t >> 6, l2 = t & 63, row = l2 & 15, k0l = kcl * 32 + (l2 >> 4) * 8;
      us8 H, L;
#pragma unroll
      for (int j = 0; j < 8; ++j) {
        unsigned short h, lo; split_bf16(U.comb.hT[k0l + j][row], h, lo);
        H[j] = h; L[j] = lo;
      }
      size_t dst = ((size_t)m * 8 + g * 2 + kcl) * 512 + l2 * 8;
      *(us8*)((ushort_t*)(ws + O_A2H) + dst) = H;
      *(us8*)((ushort_t*)(ws + O_A2L) + dst) = L;
    }
  }
  gbar(bar + 2);

  // ---------- P4: gen3 (g==0 blocks; 4 waves x 2 experts) + reduce -> out ----------
  if (g == 0) {
    const ushort_t* A2H = (const ushort_t*)(ws + O_A2H);
    const ushort_t* A2L = (const ushort_t*)(ws + O_A2L);
    for (int i = t; i < 512; i += 256) {
      int e2 = i >> 6, n = i & 63;
      U.g3.eb3L[e2][n] = (n < DOUT) ? eb3[e2 * DOUT + n] : 0.f;
    }
    bf16x8 ah[8], al[8];
#pragma unroll
    for (int kc = 0; kc < 8; ++kc) {
      ah[kc] = *(const bf16x8*)(A2H + ((size_t)m * 8 + kc) * 512 + l * 8);
      al[kc] = *(const bf16x8*)(A2L + ((size_t)m * 8 + kc) * 512 + l * 8);
    }
#pragma unroll
    for (int ee = 0; ee < 2; ++ee) {
      const int e = wv + ee * 4;
      f32x4 acc[4] = {};
#pragma unroll
      for (int kc = 0; kc < 8; ++kc) {
#pragma unroll
        for (int nsi = 0; nsi < 4; ++nsi) {
          size_t bo = (((size_t)(e * 4 + nsi)) * 8 + kc) * 512 + l * 8;
          bf16x8 bh = *(const bf16x8*)(E3H + bo);
          acc[nsi] = MFMA(ah[kc], bh, acc[nsi], 0, 0, 0);
          acc[nsi] = MFMA(al[kc], bh, acc[nsi], 0, 0, 0);
        }
      }
#pragma unroll
      for (int nsi = 0; nsi < 4; ++nsi)
#pragma unroll
        for (int r = 0; r < 4; ++r)
          U.g3.p3s[e][quad * 4 + r][nsi * 16 + c] = acc[nsi][r];
    }
    __syncthreads();
#pragma unroll
    for (int i = 0; i < 4; ++i) {
      int idx = t + i * 256;             // 1024 outputs: [16 rows][64 cols]
      int row = idx >> 6, col = idx & 63;
      float s = 0.f;
#pragma unroll
      for (int e2 = 0; e2 < 8; ++e2)
        s = fmaf(bcL[row][e2], U.g3.p3s[e2][row][col] + U.g3.eb3L[e2][col], s);
      if (col < DOUT) out[(size_t)(R0 + row) * DOUT + col] = s;
    }
  }
}

extern "C" void kernel_launch(void* const* d_in, const int* in_sizes, int n_in,
                              void* d_out, int out_size, void* d_ws, size_t ws_size,
                              hipStream_t stream) {
  const float* x      = (const float*)d_in[0];
  const float* w1     = (const float*)d_in[1];
  const float* b1     = (const float*)d_in[2];
  const float* gamma1 = (const float*)d_in[3];
  const float* beta1  = (const float*)d_in[4];
  const float* w2     = (const float*)d_in[5];
  const float* b2     = (const float*)d_in[6];
  const float* gamma2 = (const float*)d_in[7];
  const float* beta2  = (const float*)d_in[8];
  const float* gw1    = (const float*)d_in[9];
  const float* gb1    = (const float*)d_in[10];
  const float* gw2    = (const float*)d_in[11];
  const float* gb2    = (const float*)d_in[12];
  const float* gw3    = (const float*)d_in[13];
  const float* gb3    = (const float*)d_in[14];
  const float* ew1    = (const float*)d_in[15];
  const float* eb1    = (const float*)d_in[16];
  const float* ew2    = (const float*)d_in[17];
  const float* eb2    = (const float*)d_in[18];
  const float* ew3    = (const float*)d_in[19];
  const float* eb3    = (const float*)d_in[20];
  float* wsf  = (float*)d_ws;
  float* outp = (float*)d_out;

  k_prep_enc1<<<576, 256, 0, stream>>>(x, w1, b1, ew1, ew2, ew3, wsf);
  k_rest<<<256, 256, 0, stream>>>(gamma1, beta1, w2, b2, gamma2, beta2,
                                  gw1, gb1, gw2, gb2, gw3, gb3,
                                  eb1, eb2, eb3, wsf, outp);
}

// Round 5
// 170.952 us; speedup vs baseline: 1.1628x; 1.0753x over previous
//
#include <hip/hip_runtime.h>
#include <math.h>

// Network_22892175688023 — round 15: persistent k_rest, ALL-RELAXED barrier +
// targeted write-through cross-phase data. 2 stages.
//   R14 post-mortem: agent-scope ACQUIRE/RELEASE on gfx950 emit L2-wide
//   invalidate/writeback walks (per poll / per arrival!) because per-XCD L2s are
//   non-coherent. 255 spinners x inval every 0.2us saturated the L2s.
//   Fix: relaxed-only atomics (coherent point access, no cache maintenance);
//   cross-phase payload (slots2/h2raw/A1/A2, ~KBs) moved via relaxed agent
//   atomic dword stores/loads; everything crossing the K1->K2 kernel boundary
//   stays plain-cached. Numerics bit-identical to R14 (absmax 0.00390625).

#define DIN 103
#define NE  8
#define HH  256
#define DOUT 51
#define EPSBN 1e-5f

typedef __attribute__((ext_vector_type(8))) short bf16x8;
typedef __attribute__((ext_vector_type(4))) float f32x4;
typedef __attribute__((ext_vector_type(8))) unsigned short us8;
typedef unsigned short ushort_t;

__device__ __forceinline__ float eluf(float v) { return v > 0.f ? v : (expf(v) - 1.f); }
__device__ __forceinline__ unsigned short bf16h(float f) {
  unsigned u = __float_as_uint(f);
  u += 0x7FFFu + ((u >> 16) & 1u);
  return (unsigned short)(u >> 16);
}
__device__ __forceinline__ float bf16f(unsigned short h) { return __uint_as_float(((unsigned)h) << 16); }
__device__ __forceinline__ void split_bf16(float v, unsigned short& h, unsigned short& l) {
  h = bf16h(v);
  l = bf16h(v - bf16f(h));
}
#define MFMA __builtin_amdgcn_mfma_f32_16x16x32_bf16

// relaxed agent-scope coherent access helpers (no cache-maintenance ops)
__device__ __forceinline__ void stA(float* p, float v) {
  __hip_atomic_store(p, v, __ATOMIC_RELAXED, __HIP_MEMORY_SCOPE_AGENT);
}
__device__ __forceinline__ float ldA(const float* p) {
  return __hip_atomic_load((float*)p, __ATOMIC_RELAXED, __HIP_MEMORY_SCOPE_AGENT);
}
__device__ __forceinline__ void stAu(unsigned* p, unsigned v) {
  __hip_atomic_store(p, v, __ATOMIC_RELAXED, __HIP_MEMORY_SCOPE_AGENT);
}
__device__ __forceinline__ unsigned ldAu(const unsigned* p) {
  return __hip_atomic_load((unsigned*)p, __ATOMIC_RELAXED, __HIP_MEMORY_SCOPE_AGENT);
}
union U16B { us8 v; bf16x8 b; unsigned u[4]; };
__device__ __forceinline__ void st16A(void* p, us8 x) {
  U16B t; t.v = x;
  unsigned* d = (unsigned*)p;
#pragma unroll
  for (int j = 0; j < 4; ++j) stAu(d + j, t.u[j]);
}
__device__ __forceinline__ bf16x8 ld16A(const void* p) {
  U16B t;
  const unsigned* s = (const unsigned*)p;
#pragma unroll
  for (int j = 0; j < 4; ++j) t.u[j] = ldAu(s + j);
  return t.b;
}

// ---- ws layout (float offsets) ----
#define O_SLOTS1 0        // [64][128]
#define O_SLOTS2 8192     // [64][64]
#define O_H1RAW  20480    // [1024][64]
#define O_H2RAW  86016    // [1024][32]
#define O_XSH    118784   // [64 msub][4 kc][512] sh
#define O_XSL    184320
#define O_E1H    258048   // [8 e][16 ns][4 kc][512] sh
#define O_E1L    389120
#define O_E2H    520192   // [8 e][16 ns][8 kc][512] sh  (hi only)
#define O_E3H    782336   // [8 e][4 ns][8 kc][512] sh   (hi only)
#define O_A1H    847872   // [64 m][8 kc][512] sh
#define O_A1L    978944
#define O_A2H    1110016
#define O_A2L    1241088
#define O_BAR    1372160  // 4 unsigned barrier counters (zeroed by k_prep_enc1)

// all-relaxed counting barrier: per-wave store drain + s_barrier, one relaxed
// RMW arrival per block, relaxed load spin. No L2 writeback/invalidate ops.
__device__ __forceinline__ void gbar(unsigned* c) {
  asm volatile("s_waitcnt vmcnt(0)" ::: "memory");
  __syncthreads();
  if (threadIdx.x == 0) {
    __hip_atomic_fetch_add(c, 1u, __ATOMIC_RELAXED, __HIP_MEMORY_SCOPE_AGENT);
    while (__hip_atomic_load(c, __ATOMIC_RELAXED, __HIP_MEMORY_SCOPE_AGENT) < 256u)
      __builtin_amdgcn_s_sleep(2);
  }
  __syncthreads();
}

// ================= K1: prep planes + Xs frags + enc L1 (VALU) =================
// blocks: E2 0..255 | E1 256..383 | E3 384..447 | Xs 448..511 | enc1 512..575
__global__ __launch_bounds__(256) void k_prep_enc1(
    const float* __restrict__ x, const float* __restrict__ w1, const float* __restrict__ b1,
    const float* __restrict__ ew1, const float* __restrict__ ew2, const float* __restrict__ ew3,
    float* __restrict__ ws) {
  __shared__ union {
    float tile[32][65];
    float xt[16][104];
    struct { float w1L[64 * DIN]; float xr[16][104]; float hb[16][64]; } e1;
  } sm;
  int bk = blockIdx.x, t = threadIdx.x;
  int l2 = t & 63, c = l2 & 15, q = l2 >> 4;
  if (bk == 0 && t < 4) ((unsigned*)(ws + O_BAR))[t] = 0u;   // reset grid barriers

  if (bk < 256) {          // ---- E2: K=256, N=256, hi only ----
    int nh = bk & 3, kc = (bk >> 2) & 7, e = bk >> 5;
    int k0 = kc * 32, n0 = nh * 64;
#pragma unroll
    for (int i = 0; i < 8; ++i) {
      int kl = (t >> 6) + i * 4;
      sm.tile[kl][t & 63] = ew2[((size_t)e * HH + k0 + kl) * HH + n0 + (t & 63)];
    }
    __syncthreads();
    int nsl = t >> 6;
    us8 H8;
#pragma unroll
    for (int j = 0; j < 8; ++j) H8[j] = bf16h(sm.tile[q * 8 + j][nsl * 16 + c]);
    size_t dst = (((size_t)(e * 16 + nh * 4 + nsl)) * 8 + kc) * 512 + l2 * 8;
    *(us8*)((ushort_t*)(ws + O_E2H) + dst) = H8;
  } else if (bk < 384) {   // ---- E1: K=103->128, N=256, hi+lo ----
    int b2 = bk - 256;
    int nh = b2 & 3, kc = (b2 >> 2) & 3, e = b2 >> 4;
    int k0 = kc * 32, n0 = nh * 64;
#pragma unroll
    for (int i = 0; i < 8; ++i) {
      int kl = (t >> 6) + i * 4;
      int k = k0 + kl;
      sm.tile[kl][t & 63] = (k < DIN) ? ew1[((size_t)e * DIN + k) * HH + n0 + (t & 63)] : 0.f;
    }
    __syncthreads();
    int nsl = t >> 6;
    us8 H8, L8;
#pragma unroll
    for (int j = 0; j < 8; ++j) {
      unsigned short h, lo; split_bf16(sm.tile[q * 8 + j][nsl * 16 + c], h, lo);
      H8[j] = h; L8[j] = lo;
    }
    size_t dst = (((size_t)(e * 16 + nh * 4 + nsl)) * 4 + kc) * 512 + l2 * 8;
    *(us8*)((ushort_t*)(ws + O_E1H) + dst) = H8;
    *(us8*)((ushort_t*)(ws + O_E1L) + dst) = L8;
  } else if (bk < 448) {   // ---- E3: K=256, N=51->64, hi only ----
    int b2 = bk - 384;
    int kc = b2 & 7, e = b2 >> 3;
    int k0 = kc * 32;
#pragma unroll
    for (int i = 0; i < 8; ++i) {
      int kl = (t >> 6) + i * 4;
      int n = t & 63;
      sm.tile[kl][n] = (n < DOUT) ? ew3[((size_t)e * HH + k0 + kl) * DOUT + n] : 0.f;
    }
    __syncthreads();
    int nsl = t >> 6;
    us8 H8;
#pragma unroll
    for (int j = 0; j < 8; ++j) H8[j] = bf16h(sm.tile[q * 8 + j][nsl * 16 + c]);
    size_t dst = (((size_t)(e * 4 + nsl)) * 8 + kc) * 512 + l2 * 8;
    *(us8*)((ushort_t*)(ws + O_E3H) + dst) = H8;
  } else if (bk < 512) {   // ---- Xs: A-fragments of scaled x, 16 rows/block, hi+lo ----
    int msub = bk - 448;
    for (int i = t; i < 16 * 104; i += 256) {
      int b = i / 104, k = i - b * 104;
      float v = 0.f;
      if (k < DIN) { v = x[(size_t)(msub * 16 + b) * DIN + k]; if (k >= 100) v *= 100.f; }
      sm.xt[b][k] = v;
    }
    __syncthreads();
    int kc = t >> 6;
    int m = c;
    us8 H8, L8;
#pragma unroll
    for (int j = 0; j < 8; ++j) {
      int k = kc * 32 + q * 8 + j;
      float v = (k < 104) ? sm.xt[m][k] : 0.f;
      unsigned short h, lo; split_bf16(v, h, lo);
      H8[j] = h; L8[j] = lo;
    }
    size_t dst = ((size_t)msub * 4 + kc) * 512 + l2 * 8;
    *(us8*)((ushort_t*)(ws + O_XSH) + dst) = H8;
    *(us8*)((ushort_t*)(ws + O_XSL) + dst) = L8;
  } else {                 // ---- enc L1 (VALU): 16 rows/block ----
    float* slots1 = ws + O_SLOTS1;
    float* h1raw  = ws + O_H1RAW;
    int bkl = bk - 512;
    int r0 = bkl * 16;
    for (int i = t; i < 64 * DIN; i += 256) sm.e1.w1L[i] = w1[i];
    for (int i = t; i < 16 * 104; i += 256) {
      int r = i / 104, c2 = i - r * 104;
      float v = 0.f;
      if (c2 < DIN) { v = x[(size_t)(r0 + r) * DIN + c2]; if (c2 >= 100) v *= 100.f; }
      sm.e1.xr[r][c2] = v;
    }
    __syncthreads();
#pragma unroll
    for (int i = 0; i < 4; ++i) {
      int idx = t + i * 256;
      int r = idx >> 6, j = idx & 63;
      float acc = b1[j];
      for (int k = 0; k < DIN; ++k) acc = fmaf(sm.e1.xr[r][k], sm.e1.w1L[j * DIN + k], acc);
      sm.e1.hb[r][j] = acc;
      h1raw[(size_t)(r0 + r) * 64 + j] = acc;
    }
    __syncthreads();
    if (t < 64) {
      float s = 0.f, qq = 0.f;
      for (int r = 0; r < 16; ++r) { float v = sm.e1.hb[r][t]; s += v; qq += v * v; }
      slots1[bkl * 128 + t] = s;
      slots1[bkl * 128 + 64 + t] = qq;
    }
  }
}

// ================= K2: k_rest — enc2 | gate+gen1 | gen2 | gen3, grid-barriered =================
__global__ __launch_bounds__(256) void k_rest(
    const float* __restrict__ gamma1, const float* __restrict__ beta1,
    const float* __restrict__ w2, const float* __restrict__ b2,
    const float* __restrict__ gamma2, const float* __restrict__ beta2,
    const float* __restrict__ gw1, const float* __restrict__ gb1,
    const float* __restrict__ gw2, const float* __restrict__ gb2,
    const float* __restrict__ gw3, const float* __restrict__ gb3,
    const float* __restrict__ eb1, const float* __restrict__ eb2,
    const float* __restrict__ eb3,
    float* __restrict__ ws, float* __restrict__ out) {
  __shared__ union {
    struct { float w2T[64 * 33]; float red[128]; float sc1[64], sh1[64];
             float h1b[16][64]; float hb2[16][32]; } enc2;
    struct { float gw1L[64 * 33]; float gw2L[64 * 65]; float gw3L[8 * 65];
             float gb1L[64], gb2L[64], gb3L[8];
             float red2[64], sc2[32], sh2[32];
             float lat[16][32]; float g1[16][64], g2[16][64]; } gate;
    struct { float hT[64][17]; float ebs[512]; } comb;
    struct { float p3s[8][16][64]; float eb3L[8][64]; } g3;
  } U;
  __shared__ float bcL[16][8];                    // persists P2 -> P4

  const int blk = blockIdx.x, t = threadIdx.x;
  const int m = blk >> 2, g = blk & 3;
  const int wv = t >> 6, l = t & 63, c = l & 15, quad = l >> 4;
  const int R0 = m * 16;
  unsigned* bar = (unsigned*)(ws + O_BAR);
  const ushort_t* XsH = (const ushort_t*)(ws + O_XSH);
  const ushort_t* XsL = (const ushort_t*)(ws + O_XSL);
  const ushort_t* E1H = (const ushort_t*)(ws + O_E1H);
  const ushort_t* E1L = (const ushort_t*)(ws + O_E1L);
  const ushort_t* E2H = (const ushort_t*)(ws + O_E2H);
  const ushort_t* E3H = (const ushort_t*)(ws + O_E3H);

  // early A-fragment loads (produced by K1; plain cached — kernel boundary)
  bf16x8 a1h[4], a1l[4];
#pragma unroll
  for (int kc = 0; kc < 4; ++kc) {
    a1h[kc] = *(const bf16x8*)(XsH + ((size_t)m * 4 + kc) * 512 + l * 8);
    a1l[kc] = *(const bf16x8*)(XsL + ((size_t)m * 4 + kc) * 512 + l * 8);
  }

  // ---------- P1: enc2 (blocks 0..63); blocks 64+ preload gate weights ----------
  if (blk < 64) {
    float* slots1 = ws + O_SLOTS1;
    float* slots2 = ws + O_SLOTS2;
    float* h1raw  = ws + O_H1RAW;
    float* h2raw  = ws + O_H2RAW;
    const int R0e = blk * 16;
    for (int i = t; i < 2048; i += 256) { int j = i >> 6, k = i & 63; U.enc2.w2T[k * 33 + j] = w2[i]; }
    if (t < 128) {
      float s = 0.f;
      for (int b = 0; b < 64; ++b) s += slots1[b * 128 + t];
      U.enc2.red[t] = s;
    }
    __syncthreads();
    if (t < 64) {
      float mm = U.enc2.red[t] * (1.f / 1024.f);
      float v = U.enc2.red[64 + t] * (1.f / 1024.f) - mm * mm;
      float sc = gamma1[t] * rsqrtf(v + EPSBN);
      U.enc2.sc1[t] = sc; U.enc2.sh1[t] = beta1[t] - mm * sc;
    }
    __syncthreads();
#pragma unroll
    for (int i = 0; i < 4; ++i) {
      int idx = t + i * 256;
      int r = idx >> 6, k = idx & 63;
      U.enc2.h1b[r][k] = fmaxf(fmaf(h1raw[(size_t)(R0e + r) * 64 + k], U.enc2.sc1[k], U.enc2.sh1[k]), 0.f);
    }
    __syncthreads();
#pragma unroll
    for (int i = 0; i < 2; ++i) {
      int o = t + i * 256;
      int r = o >> 5, j = o & 31;
      float acc = b2[j];
      for (int k = 0; k < 64; ++k) acc = fmaf(U.enc2.h1b[r][k], U.enc2.w2T[k * 33 + j], acc);
      U.enc2.hb2[r][j] = acc;
      stA(h2raw + (size_t)(R0e + r) * 32 + j, acc);      // write-through (cross-phase)
    }
    __syncthreads();
    if (t < 32) {
      float s = 0.f, q = 0.f;
      for (int r = 0; r < 16; ++r) { float v = U.enc2.hb2[r][t]; s += v; q += v * v; }
      stA(slots2 + blk * 64 + t, s);                      // write-through (cross-phase)
      stA(slots2 + blk * 64 + 32 + t, q);
    }
  } else {
    // idle in P1: preload gate weight tiles now (U.enc2 unused in these blocks)
    for (int i = t; i < 2048; i += 256) { int j = i >> 5, k = i & 31; U.gate.gw1L[j * 33 + k] = gw1[i]; }
    for (int i = t; i < 4096; i += 256) { int j = i >> 6, k = i & 63; U.gate.gw2L[j * 65 + k] = gw2[i]; }
    for (int i = t; i < 512; i += 256) { int j = i >> 6, k = i & 63; U.gate.gw3L[j * 65 + k] = gw3[i]; }
    if (t < 64) { U.gate.gb1L[t] = gb1[t]; U.gate.gb2L[t] = gb2[t]; }
    if (t < 8) U.gate.gb3L[t] = gb3[t];
  }
  gbar(bar + 0);

  // ---------- P2: gate (redundant per msub; bit-identical) + gen1+comb1 ----------
  {
    const float* slots2 = ws + O_SLOTS2;
    const float* h2raw  = ws + O_H2RAW;
    if (blk < 64) {   // these blocks ran enc2 in P1; load gate weights now
      for (int i = t; i < 2048; i += 256) { int j = i >> 5, k = i & 31; U.gate.gw1L[j * 33 + k] = gw1[i]; }
      for (int i = t; i < 4096; i += 256) { int j = i >> 6, k = i & 63; U.gate.gw2L[j * 65 + k] = gw2[i]; }
      for (int i = t; i < 512; i += 256) { int j = i >> 6, k = i & 63; U.gate.gw3L[j * 65 + k] = gw3[i]; }
      if (t < 64) { U.gate.gb1L[t] = gb1[t]; U.gate.gb2L[t] = gb2[t]; }
      if (t < 8) U.gate.gb3L[t] = gb3[t];
    }
    if (t < 64) {
      float vvv[64];
#pragma unroll
      for (int b = 0; b < 64; ++b) vvv[b] = ldA(slots2 + b * 64 + t);   // pipelined coherent loads
      float s = 0.f;
#pragma unroll
      for (int b = 0; b < 64; ++b) s += vvv[b];            // same order as before -> bit-identical
      U.gate.red2[t] = s;
    }
    __syncthreads();
    if (t < 32) {
      float mm = U.gate.red2[t] * (1.f / 1024.f);
      float v = U.gate.red2[32 + t] * (1.f / 1024.f) - mm * mm;
      float sc = gamma2[t] * rsqrtf(v + EPSBN);
      U.gate.sc2[t] = sc; U.gate.sh2[t] = beta2[t] - mm * sc;
    }
    __syncthreads();
#pragma unroll
    for (int i = 0; i < 2; ++i) {
      int idx = t + i * 256;
      int r = idx >> 5, cc = idx & 31;
      U.gate.lat[r][cc] = fmaxf(fmaf(ldA(h2raw + (size_t)(R0 + r) * 32 + cc), U.gate.sc2[cc], U.gate.sh2[cc]), 0.f);
    }
    __syncthreads();
#pragma unroll
    for (int rr = 0; rr < 4; ++rr) {
      int r = wv * 4 + rr;
      float a1 = U.gate.gb1L[l];
      for (int k = 0; k < 32; ++k) a1 = fmaf(U.gate.gw1L[l * 33 + k], U.gate.lat[r][k], a1);
      U.gate.g1[r][l] = eluf(a1);
    }
    __syncthreads();
#pragma unroll
    for (int rr = 0; rr < 4; ++rr) {
      int r = wv * 4 + rr;
      float a2 = U.gate.gb2L[l];
      for (int k = 0; k < 64; ++k) a2 = fmaf(U.gate.gw2L[l * 65 + k], U.gate.g1[r][k], a2);
      U.gate.g2[r][l] = eluf(a2);
    }
    __syncthreads();
#pragma unroll
    for (int rr = 0; rr < 4; ++rr) {
      int r = wv * 4 + rr;
      if (l < 8) {
        float a3 = U.gate.gb3L[l];
        for (int k = 0; k < 64; ++k) a3 = fmaf(U.gate.gw3L[l * 65 + k], U.gate.g2[r][k], a3);
        float mx = a3;
        mx = fmaxf(mx, __shfl_xor(mx, 1));
        mx = fmaxf(mx, __shfl_xor(mx, 2));
        mx = fmaxf(mx, __shfl_xor(mx, 4));
        float p = expf(a3 - mx);
        float sp = p;
        sp += __shfl_xor(sp, 1); sp += __shfl_xor(sp, 2); sp += __shfl_xor(sp, 4);
        bcL[r][l] = p / sp;
      }
    }
    __syncthreads();   // gate done; union reused below

    // gen1 + comb1 for cols [g*64, g*64+64)
    for (int i = t; i < 512; i += 256) U.comb.ebs[i] = eb1[(i >> 6) * HH + g * 64 + (i & 63)];
    __syncthreads();
    const int ns = g * 4 + wv;
    f32x4 blend = {};
#pragma unroll
    for (int e = 0; e < NE; ++e) {
      float bcv[4];
#pragma unroll
      for (int r = 0; r < 4; ++r) bcv[r] = bcL[quad * 4 + r][e];
      f32x4 acc = {};
#pragma unroll
      for (int kc = 0; kc < 4; ++kc) {
        size_t bo = (((size_t)(e * 16 + ns)) * 4 + kc) * 512 + l * 8;
        bf16x8 bh = *(const bf16x8*)(E1H + bo);
        bf16x8 bl = *(const bf16x8*)(E1L + bo);
        acc = MFMA(a1h[kc], bh, acc, 0, 0, 0);
        acc = MFMA(a1l[kc], bh, acc, 0, 0, 0);
        acc = MFMA(a1h[kc], bl, acc, 0, 0, 0);
      }
      float ebv = U.comb.ebs[e * 64 + wv * 16 + c];
#pragma unroll
      for (int r = 0; r < 4; ++r) blend[r] = fmaf(bcv[r], acc[r] + ebv, blend[r]);
    }
#pragma unroll
    for (int r = 0; r < 4; ++r) U.comb.hT[wv * 16 + c][quad * 4 + r] = eluf(blend[r]);
    __syncthreads();
    if (t < 128) {   // repack 64 cols -> A1 fragment chunks kc = 2g, 2g+1 (write-through)
      int kcl = t >> 6, l2 = t & 63, row = l2 & 15, k0l = kcl * 32 + (l2 >> 4) * 8;
      us8 H, L;
#pragma unroll
      for (int j = 0; j < 8; ++j) {
        unsigned short h, lo; split_bf16(U.comb.hT[k0l + j][row], h, lo);
        H[j] = h; L[j] = lo;
      }
      size_t dst = ((size_t)m * 8 + g * 2 + kcl) * 512 + l2 * 8;
      st16A((ushort_t*)(ws + O_A1H) + dst, H);
      st16A((ushort_t*)(ws + O_A1L) + dst, L);
    }
  }
  gbar(bar + 1);

  // ---------- P3: gen2 + comb2 for cols [g*64, g*64+64) ----------
  {
    const ushort_t* A1H = (const ushort_t*)(ws + O_A1H);
    const ushort_t* A1L = (const ushort_t*)(ws + O_A1L);
    for (int i = t; i < 512; i += 256) U.comb.ebs[i] = eb2[(i >> 6) * HH + g * 64 + (i & 63)];
    bf16x8 ah[8], al[8];
#pragma unroll
    for (int kc = 0; kc < 8; ++kc) {
      ah[kc] = ld16A(A1H + ((size_t)m * 8 + kc) * 512 + l * 8);
      al[kc] = ld16A(A1L + ((size_t)m * 8 + kc) * 512 + l * 8);
    }
    __syncthreads();
    const int ns = g * 4 + wv;
    f32x4 blend = {};
#pragma unroll
    for (int e = 0; e < NE; ++e) {
      float bcv[4];
#pragma unroll
      for (int r = 0; r < 4; ++r) bcv[r] = bcL[quad * 4 + r][e];
      f32x4 acc = {};
#pragma unroll
      for (int kc = 0; kc < 8; ++kc) {
        size_t bo = (((size_t)(e * 16 + ns)) * 8 + kc) * 512 + l * 8;
        bf16x8 bh = *(const bf16x8*)(E2H + bo);
        acc = MFMA(ah[kc], bh, acc, 0, 0, 0);
        acc = MFMA(al[kc], bh, acc, 0, 0, 0);
      }
      float ebv = U.comb.ebs[e * 64 + wv * 16 + c];
#pragma unroll
      for (int r = 0; r < 4; ++r) blend[r] = fmaf(bcv[r], acc[r] + ebv, blend[r]);
    }
#pragma unroll
    for (int r = 0; r < 4; ++r) U.comb.hT[wv * 16 + c][quad * 4 + r] = eluf(blend[r]);
    __syncthreads();
    if (t < 128) {
      int kcl = t >> 6, l2 = t & 63, row = l2 & 15, k0l = kcl * 32 + (l2 >> 4) * 8;
      us8 H, L;
#pragma unroll
      for (int j = 0; j < 8; ++j) {
        unsigned short h, lo; split_bf16(U.comb.hT[k0l + j][row], h, lo);
        H[j] = h; L[j] = lo;
      }
      size_t dst = ((size_t)m * 8 + g * 2 + kcl) * 512 + l2 * 8;
      st16A((ushort_t*)(ws + O_A2H) + dst, H);
      st16A((ushort_t*)(ws + O_A2L) + dst, L);
    }
  }
  gbar(bar + 2);

  // ---------- P4: gen3 (g==0 blocks; 4 waves x 2 experts) + reduce -> out ----------
  if (g == 0) {
    const ushort_t* A2H = (const ushort_t*)(ws + O_A2H);
    const ushort_t* A2L = (const ushort_t*)(ws + O_A2L);
    for (int i = t; i < 512; i += 256) {
      int e2 = i >> 6, n = i & 63;
      U.g3.eb3L[e2][n] = (n < DOUT) ? eb3[e2 * DOUT + n] : 0.f;
    }
    bf16x8 ah[8], al[8];
#pragma unroll
    for (int kc = 0; kc < 8; ++kc) {
      ah[kc] = ld16A(A2H + ((size_t)m * 8 + kc) * 512 + l * 8);
      al[kc] = ld16A(A2L + ((size_t)m * 8 + kc) * 512 + l * 8);
    }
#pragma unroll
    for (int ee = 0; ee < 2; ++ee) {
      const int e = wv + ee * 4;
      f32x4 acc[4] = {};
#pragma unroll
      for (int kc = 0; kc < 8; ++kc) {
#pragma unroll
        for (int nsi = 0; nsi < 4; ++nsi) {
          size_t bo = (((size_t)(e * 4 + nsi)) * 8 + kc) * 512 + l * 8;
          bf16x8 bh = *(const bf16x8*)(E3H + bo);
          acc[nsi] = MFMA(ah[kc], bh, acc[nsi], 0, 0, 0);
          acc[nsi] = MFMA(al[kc], bh, acc[nsi], 0, 0, 0);
        }
      }
#pragma unroll
      for (int nsi = 0; nsi < 4; ++nsi)
#pragma unroll
        for (int r = 0; r < 4; ++r)
          U.g3.p3s[e][quad * 4 + r][nsi * 16 + c] = acc[nsi][r];
    }
    __syncthreads();
#pragma unroll
    for (int i = 0; i < 4; ++i) {
      int idx = t + i * 256;             // 1024 outputs: [16 rows][64 cols]
      int row = idx >> 6, col = idx & 63;
      float s = 0.f;
#pragma unroll
      for (int e2 = 0; e2 < 8; ++e2)
        s = fmaf(bcL[row][e2], U.g3.p3s[e2][row][col] + U.g3.eb3L[e2][col], s);
      if (col < DOUT) out[(size_t)(R0 + row) * DOUT + col] = s;
    }
  }
}

extern "C" void kernel_launch(void* const* d_in, const int* in_sizes, int n_in,
                              void* d_out, int out_size, void* d_ws, size_t ws_size,
                              hipStream_t stream) {
  const float* x      = (const float*)d_in[0];
  const float* w1     = (const float*)d_in[1];
  const float* b1     = (const float*)d_in[2];
  const float* gamma1 = (const float*)d_in[3];
  const float* beta1  = (const float*)d_in[4];
  const float* w2     = (const float*)d_in[5];
  const float* b2     = (const float*)d_in[6];
  const float* gamma2 = (const float*)d_in[7];
  const float* beta2  = (const float*)d_in[8];
  const float* gw1    = (const float*)d_in[9];
  const float* gb1    = (const float*)d_in[10];
  const float* gw2    = (const float*)d_in[11];
  const float* gb2    = (const float*)d_in[12];
  const float* gw3    = (const float*)d_in[13];
  const float* gb3    = (const float*)d_in[14];
  const float* ew1    = (const float*)d_in[15];
  const float* eb1    = (const float*)d_in[16];
  const float* ew2    = (const float*)d_in[17];
  const float* eb2    = (const float*)d_in[18];
  const float* ew3    = (const float*)d_in[19];
  const float* eb3    = (const float*)d_in[20];
  float* wsf  = (float*)d_ws;
  float* outp = (float*)d_out;

  k_prep_enc1<<<576, 256, 0, stream>>>(x, w1, b1, ew1, ew2, ew3, wsf);
  k_rest<<<256, 256, 0, stream>>>(gamma1, beta1, w2, b2, gamma2, beta2,
                                  gw1, gb1, gw2, gb2, gw3, gb3,
                                  eb1, eb2, eb3, wsf, outp);
}

// Round 6
// 159.881 us; speedup vs baseline: 1.2433x; 1.0692x over previous
//
#include <hip/hip_runtime.h>
#include <math.h>

// Network_22892175688023 — round 16: persistent k_rest, TREE barrier. 2 stages.
//   R15 post-mortem: poll fixed (relaxed load) but ARRIVAL still 256 same-line
//   RMWs -> ~15-20us serialization per barrier at the LLC. Fix: 16x16 tree
//   arrival (16 group lines + 16 root RMWs) + 8 line-spread release flags,
//   32 read-pollers each. Cross-phase payload stays on R15's write-through path.
//   Compute bodies bit-identical to R15 (absmax 0.00390625).

#define DIN 103
#define NE  8
#define HH  256
#define DOUT 51
#define EPSBN 1e-5f

typedef __attribute__((ext_vector_type(8))) short bf16x8;
typedef __attribute__((ext_vector_type(4))) float f32x4;
typedef __attribute__((ext_vector_type(8))) unsigned short us8;
typedef unsigned short ushort_t;

__device__ __forceinline__ float eluf(float v) { return v > 0.f ? v : (expf(v) - 1.f); }
__device__ __forceinline__ unsigned short bf16h(float f) {
  unsigned u = __float_as_uint(f);
  u += 0x7FFFu + ((u >> 16) & 1u);
  return (unsigned short)(u >> 16);
}
__device__ __forceinline__ float bf16f(unsigned short h) { return __uint_as_float(((unsigned)h) << 16); }
__device__ __forceinline__ void split_bf16(float v, unsigned short& h, unsigned short& l) {
  h = bf16h(v);
  l = bf16h(v - bf16f(h));
}
#define MFMA __builtin_amdgcn_mfma_f32_16x16x32_bf16

// relaxed agent-scope coherent access helpers (no cache-maintenance ops)
__device__ __forceinline__ void stA(float* p, float v) {
  __hip_atomic_store(p, v, __ATOMIC_RELAXED, __HIP_MEMORY_SCOPE_AGENT);
}
__device__ __forceinline__ float ldA(const float* p) {
  return __hip_atomic_load((float*)p, __ATOMIC_RELAXED, __HIP_MEMORY_SCOPE_AGENT);
}
__device__ __forceinline__ void stAu(unsigned* p, unsigned v) {
  __hip_atomic_store(p, v, __ATOMIC_RELAXED, __HIP_MEMORY_SCOPE_AGENT);
}
__device__ __forceinline__ unsigned ldAu(const unsigned* p) {
  return __hip_atomic_load((unsigned*)p, __ATOMIC_RELAXED, __HIP_MEMORY_SCOPE_AGENT);
}
union U16B { us8 v; bf16x8 b; unsigned u[4]; };
__device__ __forceinline__ void st16A(void* p, us8 x) {
  U16B t; t.v = x;
  unsigned* d = (unsigned*)p;
#pragma unroll
  for (int j = 0; j < 4; ++j) stAu(d + j, t.u[j]);
}
__device__ __forceinline__ bf16x8 ld16A(const void* p) {
  U16B t;
  const unsigned* s = (const unsigned*)p;
#pragma unroll
  for (int j = 0; j < 4; ++j) t.u[j] = ldAu(s + j);
  return t.b;
}

// ---- ws layout (float offsets) ----
#define O_SLOTS1 0        // [64][128]
#define O_SLOTS2 8192     // [64][64]
#define O_H1RAW  20480    // [1024][64]
#define O_H2RAW  86016    // [1024][32]
#define O_XSH    118784   // [64 msub][4 kc][512] sh
#define O_XSL    184320
#define O_E1H    258048   // [8 e][16 ns][4 kc][512] sh
#define O_E1L    389120
#define O_E2H    520192   // [8 e][16 ns][8 kc][512] sh  (hi only)
#define O_E3H    782336   // [8 e][4 ns][8 kc][512] sh   (hi only)
#define O_A1H    847872   // [64 m][8 kc][512] sh
#define O_A1L    978944
#define O_A2H    1110016
#define O_A2L    1241088
#define O_BAR    1372160  // 3 x 1024-dword tree-barrier regions (zeroed by K1)

// Two-level tree barrier. Region layout (dwords): grp[i]@i*16 (i<16),
// root@256, rel[j]@272+j*16 (j<8). Each region used once per launch.
__device__ __forceinline__ void gbar(unsigned* base, int blk) {
  asm volatile("s_waitcnt vmcnt(0)" ::: "memory");
  __syncthreads();
  if (threadIdx.x == 0) {
    unsigned a = __hip_atomic_fetch_add(base + (blk >> 4) * 16, 1u,
                                        __ATOMIC_RELAXED, __HIP_MEMORY_SCOPE_AGENT);
    if (a == 15u) {                               // 16th arriver of this group
      unsigned r = __hip_atomic_fetch_add(base + 256, 1u,
                                          __ATOMIC_RELAXED, __HIP_MEMORY_SCOPE_AGENT);
      if (r == 15u) {                             // last group -> broadcast
#pragma unroll
        for (int j = 0; j < 8; ++j) stAu(base + 272 + j * 16, 1u);
      }
    }
    while (ldAu(base + 272 + (blk & 7) * 16) == 0u)
      __builtin_amdgcn_s_sleep(16);
  }
  __syncthreads();
}

// ================= K1: prep planes + Xs frags + enc L1 (VALU) =================
// blocks: E2 0..255 | E1 256..383 | E3 384..447 | Xs 448..511 | enc1 512..575
__global__ __launch_bounds__(256) void k_prep_enc1(
    const float* __restrict__ x, const float* __restrict__ w1, const float* __restrict__ b1,
    const float* __restrict__ ew1, const float* __restrict__ ew2, const float* __restrict__ ew3,
    float* __restrict__ ws) {
  __shared__ union {
    float tile[32][65];
    float xt[16][104];
    struct { float w1L[64 * DIN]; float xr[16][104]; float hb[16][64]; } e1;
  } sm;
  int bk = blockIdx.x, t = threadIdx.x;
  int l2 = t & 63, c = l2 & 15, q = l2 >> 4;
  if (bk < 3) {   // zero this launch's barrier regions (1024 dwords each)
    unsigned* bz = (unsigned*)(ws + O_BAR) + bk * 1024;
#pragma unroll
    for (int i = 0; i < 4; ++i) bz[t + i * 256] = 0u;
  }

  if (bk < 256) {          // ---- E2: K=256, N=256, hi only ----
    int nh = bk & 3, kc = (bk >> 2) & 7, e = bk >> 5;
    int k0 = kc * 32, n0 = nh * 64;
#pragma unroll
    for (int i = 0; i < 8; ++i) {
      int kl = (t >> 6) + i * 4;
      sm.tile[kl][t & 63] = ew2[((size_t)e * HH + k0 + kl) * HH + n0 + (t & 63)];
    }
    __syncthreads();
    int nsl = t >> 6;
    us8 H8;
#pragma unroll
    for (int j = 0; j < 8; ++j) H8[j] = bf16h(sm.tile[q * 8 + j][nsl * 16 + c]);
    size_t dst = (((size_t)(e * 16 + nh * 4 + nsl)) * 8 + kc) * 512 + l2 * 8;
    *(us8*)((ushort_t*)(ws + O_E2H) + dst) = H8;
  } else if (bk < 384) {   // ---- E1: K=103->128, N=256, hi+lo ----
    int b2 = bk - 256;
    int nh = b2 & 3, kc = (b2 >> 2) & 3, e = b2 >> 4;
    int k0 = kc * 32, n0 = nh * 64;
#pragma unroll
    for (int i = 0; i < 8; ++i) {
      int kl = (t >> 6) + i * 4;
      int k = k0 + kl;
      sm.tile[kl][t & 63] = (k < DIN) ? ew1[((size_t)e * DIN + k) * HH + n0 + (t & 63)] : 0.f;
    }
    __syncthreads();
    int nsl = t >> 6;
    us8 H8, L8;
#pragma unroll
    for (int j = 0; j < 8; ++j) {
      unsigned short h, lo; split_bf16(sm.tile[q * 8 + j][nsl * 16 + c], h, lo);
      H8[j] = h; L8[j] = lo;
    }
    size_t dst = (((size_t)(e * 16 + nh * 4 + nsl)) * 4 + kc) * 512 + l2 * 8;
    *(us8*)((ushort_t*)(ws + O_E1H) + dst) = H8;
    *(us8*)((ushort_t*)(ws + O_E1L) + dst) = L8;
  } else if (bk < 448) {   // ---- E3: K=256, N=51->64, hi only ----
    int b2 = bk - 384;
    int kc = b2 & 7, e = b2 >> 3;
    int k0 = kc * 32;
#pragma unroll
    for (int i = 0; i < 8; ++i) {
      int kl = (t >> 6) + i * 4;
      int n = t & 63;
      sm.tile[kl][n] = (n < DOUT) ? ew3[((size_t)e * HH + k0 + kl) * DOUT + n] : 0.f;
    }
    __syncthreads();
    int nsl = t >> 6;
    us8 H8;
#pragma unroll
    for (int j = 0; j < 8; ++j) H8[j] = bf16h(sm.tile[q * 8 + j][nsl * 16 + c]);
    size_t dst = (((size_t)(e * 4 + nsl)) * 8 + kc) * 512 + l2 * 8;
    *(us8*)((ushort_t*)(ws + O_E3H) + dst) = H8;
  } else if (bk < 512) {   // ---- Xs: A-fragments of scaled x, 16 rows/block, hi+lo ----
    int msub = bk - 448;
    for (int i = t; i < 16 * 104; i += 256) {
      int b = i / 104, k = i - b * 104;
      float v = 0.f;
      if (k < DIN) { v = x[(size_t)(msub * 16 + b) * DIN + k]; if (k >= 100) v *= 100.f; }
      sm.xt[b][k] = v;
    }
    __syncthreads();
    int kc = t >> 6;
    int m = c;
    us8 H8, L8;
#pragma unroll
    for (int j = 0; j < 8; ++j) {
      int k = kc * 32 + q * 8 + j;
      float v = (k < 104) ? sm.xt[m][k] : 0.f;
      unsigned short h, lo; split_bf16(v, h, lo);
      H8[j] = h; L8[j] = lo;
    }
    size_t dst = ((size_t)msub * 4 + kc) * 512 + l2 * 8;
    *(us8*)((ushort_t*)(ws + O_XSH) + dst) = H8;
    *(us8*)((ushort_t*)(ws + O_XSL) + dst) = L8;
  } else {                 // ---- enc L1 (VALU): 16 rows/block ----
    float* slots1 = ws + O_SLOTS1;
    float* h1raw  = ws + O_H1RAW;
    int bkl = bk - 512;
    int r0 = bkl * 16;
    for (int i = t; i < 64 * DIN; i += 256) sm.e1.w1L[i] = w1[i];
    for (int i = t; i < 16 * 104; i += 256) {
      int r = i / 104, c2 = i - r * 104;
      float v = 0.f;
      if (c2 < DIN) { v = x[(size_t)(r0 + r) * DIN + c2]; if (c2 >= 100) v *= 100.f; }
      sm.e1.xr[r][c2] = v;
    }
    __syncthreads();
#pragma unroll
    for (int i = 0; i < 4; ++i) {
      int idx = t + i * 256;
      int r = idx >> 6, j = idx & 63;
      float acc = b1[j];
      for (int k = 0; k < DIN; ++k) acc = fmaf(sm.e1.xr[r][k], sm.e1.w1L[j * DIN + k], acc);
      sm.e1.hb[r][j] = acc;
      h1raw[(size_t)(r0 + r) * 64 + j] = acc;
    }
    __syncthreads();
    if (t < 64) {
      float s = 0.f, qq = 0.f;
      for (int r = 0; r < 16; ++r) { float v = sm.e1.hb[r][t]; s += v; qq += v * v; }
      slots1[bkl * 128 + t] = s;
      slots1[bkl * 128 + 64 + t] = qq;
    }
  }
}

// ================= K2: k_rest — enc2 | gate+gen1 | gen2 | gen3, grid-barriered =================
__global__ __launch_bounds__(256) void k_rest(
    const float* __restrict__ gamma1, const float* __restrict__ beta1,
    const float* __restrict__ w2, const float* __restrict__ b2,
    const float* __restrict__ gamma2, const float* __restrict__ beta2,
    const float* __restrict__ gw1, const float* __restrict__ gb1,
    const float* __restrict__ gw2, const float* __restrict__ gb2,
    const float* __restrict__ gw3, const float* __restrict__ gb3,
    const float* __restrict__ eb1, const float* __restrict__ eb2,
    const float* __restrict__ eb3,
    float* __restrict__ ws, float* __restrict__ out) {
  __shared__ union {
    struct { float w2T[64 * 33]; float red[128]; float sc1[64], sh1[64];
             float h1b[16][64]; float hb2[16][32]; } enc2;
    struct { float gw1L[64 * 33]; float gw2L[64 * 65]; float gw3L[8 * 65];
             float gb1L[64], gb2L[64], gb3L[8];
             float red2[64], sc2[32], sh2[32];
             float lat[16][32]; float g1[16][64], g2[16][64]; } gate;
    struct { float hT[64][17]; float ebs[512]; } comb;
    struct { float p3s[8][16][64]; float eb3L[8][64]; } g3;
  } U;
  __shared__ float bcL[16][8];                    // persists P2 -> P4

  const int blk = blockIdx.x, t = threadIdx.x;
  const int m = blk >> 2, g = blk & 3;
  const int wv = t >> 6, l = t & 63, c = l & 15, quad = l >> 4;
  const int R0 = m * 16;
  unsigned* bar = (unsigned*)(ws + O_BAR);
  const ushort_t* XsH = (const ushort_t*)(ws + O_XSH);
  const ushort_t* XsL = (const ushort_t*)(ws + O_XSL);
  const ushort_t* E1H = (const ushort_t*)(ws + O_E1H);
  const ushort_t* E1L = (const ushort_t*)(ws + O_E1L);
  const ushort_t* E2H = (const ushort_t*)(ws + O_E2H);
  const ushort_t* E3H = (const ushort_t*)(ws + O_E3H);

  // early A-fragment loads (produced by K1; plain cached — kernel boundary)
  bf16x8 a1h[4], a1l[4];
#pragma unroll
  for (int kc = 0; kc < 4; ++kc) {
    a1h[kc] = *(const bf16x8*)(XsH + ((size_t)m * 4 + kc) * 512 + l * 8);
    a1l[kc] = *(const bf16x8*)(XsL + ((size_t)m * 4 + kc) * 512 + l * 8);
  }

  // ---------- P1: enc2 (blocks 0..63); blocks 64+ preload gate weights ----------
  if (blk < 64) {
    float* slots1 = ws + O_SLOTS1;
    float* slots2 = ws + O_SLOTS2;
    float* h1raw  = ws + O_H1RAW;
    float* h2raw  = ws + O_H2RAW;
    const int R0e = blk * 16;
    for (int i = t; i < 2048; i += 256) { int j = i >> 6, k = i & 63; U.enc2.w2T[k * 33 + j] = w2[i]; }
    if (t < 128) {
      float s = 0.f;
#pragma unroll
      for (int ch = 0; ch < 2; ++ch) {           // chunked-32 pipelined loads, same order
        float arr[32];
#pragma unroll
        for (int b = 0; b < 32; ++b) arr[b] = slots1[(ch * 32 + b) * 128 + t];
#pragma unroll
        for (int b = 0; b < 32; ++b) s += arr[b];
      }
      U.enc2.red[t] = s;
    }
    __syncthreads();
    if (t < 64) {
      float mm = U.enc2.red[t] * (1.f / 1024.f);
      float v = U.enc2.red[64 + t] * (1.f / 1024.f) - mm * mm;
      float sc = gamma1[t] * rsqrtf(v + EPSBN);
      U.enc2.sc1[t] = sc; U.enc2.sh1[t] = beta1[t] - mm * sc;
    }
    __syncthreads();
#pragma unroll
    for (int i = 0; i < 4; ++i) {
      int idx = t + i * 256;
      int r = idx >> 6, k = idx & 63;
      U.enc2.h1b[r][k] = fmaxf(fmaf(h1raw[(size_t)(R0e + r) * 64 + k], U.enc2.sc1[k], U.enc2.sh1[k]), 0.f);
    }
    __syncthreads();
#pragma unroll
    for (int i = 0; i < 2; ++i) {
      int o = t + i * 256;
      int r = o >> 5, j = o & 31;
      float acc = b2[j];
      for (int k = 0; k < 64; ++k) acc = fmaf(U.enc2.h1b[r][k], U.enc2.w2T[k * 33 + j], acc);
      U.enc2.hb2[r][j] = acc;
      stA(h2raw + (size_t)(R0e + r) * 32 + j, acc);      // write-through (cross-phase)
    }
    __syncthreads();
    if (t < 32) {
      float s = 0.f, q = 0.f;
      for (int r = 0; r < 16; ++r) { float v = U.enc2.hb2[r][t]; s += v; q += v * v; }
      stA(slots2 + blk * 64 + t, s);                      // write-through (cross-phase)
      stA(slots2 + blk * 64 + 32 + t, q);
    }
  } else {
    // idle in P1: preload gate weight tiles now (U.enc2 unused in these blocks)
    for (int i = t; i < 2048; i += 256) { int j = i >> 5, k = i & 31; U.gate.gw1L[j * 33 + k] = gw1[i]; }
    for (int i = t; i < 4096; i += 256) { int j = i >> 6, k = i & 63; U.gate.gw2L[j * 65 + k] = gw2[i]; }
    for (int i = t; i < 512; i += 256) { int j = i >> 6, k = i & 63; U.gate.gw3L[j * 65 + k] = gw3[i]; }
    if (t < 64) { U.gate.gb1L[t] = gb1[t]; U.gate.gb2L[t] = gb2[t]; }
    if (t < 8) U.gate.gb3L[t] = gb3[t];
  }
  gbar(bar, blk);

  // ---------- P2: gate (redundant per msub; bit-identical) + gen1+comb1 ----------
  {
    const float* slots2 = ws + O_SLOTS2;
    const float* h2raw  = ws + O_H2RAW;
    if (blk < 64) {   // these blocks ran enc2 in P1; load gate weights now
      for (int i = t; i < 2048; i += 256) { int j = i >> 5, k = i & 31; U.gate.gw1L[j * 33 + k] = gw1[i]; }
      for (int i = t; i < 4096; i += 256) { int j = i >> 6, k = i & 63; U.gate.gw2L[j * 65 + k] = gw2[i]; }
      for (int i = t; i < 512; i += 256) { int j = i >> 6, k = i & 63; U.gate.gw3L[j * 65 + k] = gw3[i]; }
      if (t < 64) { U.gate.gb1L[t] = gb1[t]; U.gate.gb2L[t] = gb2[t]; }
      if (t < 8) U.gate.gb3L[t] = gb3[t];
    }
    if (t < 64) {
      float vvv[64];
#pragma unroll
      for (int b = 0; b < 64; ++b) vvv[b] = ldA(slots2 + b * 64 + t);   // pipelined coherent loads
      float s = 0.f;
#pragma unroll
      for (int b = 0; b < 64; ++b) s += vvv[b];            // same order as before -> bit-identical
      U.gate.red2[t] = s;
    }
    __syncthreads();
    if (t < 32) {
      float mm = U.gate.red2[t] * (1.f / 1024.f);
      float v = U.gate.red2[32 + t] * (1.f / 1024.f) - mm * mm;
      float sc = gamma2[t] * rsqrtf(v + EPSBN);
      U.gate.sc2[t] = sc; U.gate.sh2[t] = beta2[t] - mm * sc;
    }
    __syncthreads();
#pragma unroll
    for (int i = 0; i < 2; ++i) {
      int idx = t + i * 256;
      int r = idx >> 5, cc = idx & 31;
      U.gate.lat[r][cc] = fmaxf(fmaf(ldA(h2raw + (size_t)(R0 + r) * 32 + cc), U.gate.sc2[cc], U.gate.sh2[cc]), 0.f);
    }
    __syncthreads();
#pragma unroll
    for (int rr = 0; rr < 4; ++rr) {
      int r = wv * 4 + rr;
      float a1 = U.gate.gb1L[l];
      for (int k = 0; k < 32; ++k) a1 = fmaf(U.gate.gw1L[l * 33 + k], U.gate.lat[r][k], a1);
      U.gate.g1[r][l] = eluf(a1);
    }
    __syncthreads();
#pragma unroll
    for (int rr = 0; rr < 4; ++rr) {
      int r = wv * 4 + rr;
      float a2 = U.gate.gb2L[l];
      for (int k = 0; k < 64; ++k) a2 = fmaf(U.gate.gw2L[l * 65 + k], U.gate.g1[r][k], a2);
      U.gate.g2[r][l] = eluf(a2);
    }
    __syncthreads();
#pragma unroll
    for (int rr = 0; rr < 4; ++rr) {
      int r = wv * 4 + rr;
      if (l < 8) {
        float a3 = U.gate.gb3L[l];
        for (int k = 0; k < 64; ++k) a3 = fmaf(U.gate.gw3L[l * 65 + k], U.gate.g2[r][k], a3);
        float mx = a3;
        mx = fmaxf(mx, __shfl_xor(mx, 1));
        mx = fmaxf(mx, __shfl_xor(mx, 2));
        mx = fmaxf(mx, __shfl_xor(mx, 4));
        float p = expf(a3 - mx);
        float sp = p;
        sp += __shfl_xor(sp, 1); sp += __shfl_xor(sp, 2); sp += __shfl_xor(sp, 4);
        bcL[r][l] = p / sp;
      }
    }
    __syncthreads();   // gate done; union reused below

    // gen1 + comb1 for cols [g*64, g*64+64)
    for (int i = t; i < 512; i += 256) U.comb.ebs[i] = eb1[(i >> 6) * HH + g * 64 + (i & 63)];
    __syncthreads();
    const int ns = g * 4 + wv;
    f32x4 blend = {};
#pragma unroll
    for (int e = 0; e < NE; ++e) {
      float bcv[4];
#pragma unroll
      for (int r = 0; r < 4; ++r) bcv[r] = bcL[quad * 4 + r][e];
      f32x4 acc = {};
#pragma unroll
      for (int kc = 0; kc < 4; ++kc) {
        size_t bo = (((size_t)(e * 16 + ns)) * 4 + kc) * 512 + l * 8;
        bf16x8 bh = *(const bf16x8*)(E1H + bo);
        bf16x8 bl = *(const bf16x8*)(E1L + bo);
        acc = MFMA(a1h[kc], bh, acc, 0, 0, 0);
        acc = MFMA(a1l[kc], bh, acc, 0, 0, 0);
        acc = MFMA(a1h[kc], bl, acc, 0, 0, 0);
      }
      float ebv = U.comb.ebs[e * 64 + wv * 16 + c];
#pragma unroll
      for (int r = 0; r < 4; ++r) blend[r] = fmaf(bcv[r], acc[r] + ebv, blend[r]);
    }
#pragma unroll
    for (int r = 0; r < 4; ++r) U.comb.hT[wv * 16 + c][quad * 4 + r] = eluf(blend[r]);
    __syncthreads();
    if (t < 128) {   // repack 64 cols -> A1 fragment chunks kc = 2g, 2g+1 (write-through)
      int kcl = t >> 6, l2 = t & 63, row = l2 & 15, k0l = kcl * 32 + (l2 >> 4) * 8;
      us8 H, L;
#pragma unroll
      for (int j = 0; j < 8; ++j) {
        unsigned short h, lo; split_bf16(U.comb.hT[k0l + j][row], h, lo);
        H[j] = h; L[j] = lo;
      }
      size_t dst = ((size_t)m * 8 + g * 2 + kcl) * 512 + l2 * 8;
      st16A((ushort_t*)(ws + O_A1H) + dst, H);
      st16A((ushort_t*)(ws + O_A1L) + dst, L);
    }
  }
  gbar(bar + 1024, blk);

  // ---------- P3: gen2 + comb2 for cols [g*64, g*64+64) ----------
  {
    const ushort_t* A1H = (const ushort_t*)(ws + O_A1H);
    const ushort_t* A1L = (const ushort_t*)(ws + O_A1L);
    for (int i = t; i < 512; i += 256) U.comb.ebs[i] = eb2[(i >> 6) * HH + g * 64 + (i & 63)];
    bf16x8 ah[8], al[8];
#pragma unroll
    for (int kc = 0; kc < 8; ++kc) {
      ah[kc] = ld16A(A1H + ((size_t)m * 8 + kc) * 512 + l * 8);
      al[kc] = ld16A(A1L + ((size_t)m * 8 + kc) * 512 + l * 8);
    }
    __syncthreads();
    const int ns = g * 4 + wv;
    f32x4 blend = {};
#pragma unroll
    for (int e = 0; e < NE; ++e) {
      float bcv[4];
#pragma unroll
      for (int r = 0; r < 4; ++r) bcv[r] = bcL[quad * 4 + r][e];
      f32x4 acc = {};
#pragma unroll
      for (int kc = 0; kc < 8; ++kc) {
        size_t bo = (((size_t)(e * 16 + ns)) * 8 + kc) * 512 + l * 8;
        bf16x8 bh = *(const bf16x8*)(E2H + bo);
        acc = MFMA(ah[kc], bh, acc, 0, 0, 0);
        acc = MFMA(al[kc], bh, acc, 0, 0, 0);
      }
      float ebv = U.comb.ebs[e * 64 + wv * 16 + c];
#pragma unroll
      for (int r = 0; r < 4; ++r) blend[r] = fmaf(bcv[r], acc[r] + ebv, blend[r]);
    }
#pragma unroll
    for (int r = 0; r < 4; ++r) U.comb.hT[wv * 16 + c][quad * 4 + r] = eluf(blend[r]);
    __syncthreads();
    if (t < 128) {
      int kcl = t >> 6, l2 = t & 63, row = l2 & 15, k0l = kcl * 32 + (l2 >> 4) * 8;
      us8 H, L;
#pragma unroll
      for (int j = 0; j < 8; ++j) {
        unsigned short h, lo; split_bf16(U.comb.hT[k0l + j][row], h, lo);
        H[j] = h; L[j] = lo;
      }
      size_t dst = ((size_t)m * 8 + g * 2 + kcl) * 512 + l2 * 8;
      st16A((ushort_t*)(ws + O_A2H) + dst, H);
      st16A((ushort_t*)(ws + O_A2L) + dst, L);
    }
  }
  gbar(bar + 2048, blk);

  // ---------- P4: gen3 (g==0 blocks; 4 waves x 2 experts) + reduce -> out ----------
  if (g == 0) {
    const ushort_t* A2H = (const ushort_t*)(ws + O_A2H);
    const ushort_t* A2L = (const ushort_t*)(ws + O_A2L);
    for (int i = t; i < 512; i += 256) {
      int e2 = i >> 6, n = i & 63;
      U.g3.eb3L[e2][n] = (n < DOUT) ? eb3[e2 * DOUT + n] : 0.f;
    }
    bf16x8 ah[8], al[8];
#pragma unroll
    for (int kc = 0; kc < 8; ++kc) {
      ah[kc] = ld16A(A2H + ((size_t)m * 8 + kc) * 512 + l * 8);
      al[kc] = ld16A(A2L + ((size_t)m * 8 + kc) * 512 + l * 8);
    }
#pragma unroll
    for (int ee = 0; ee < 2; ++ee) {
      const int e = wv + ee * 4;
      f32x4 acc[4] = {};
#pragma unroll
      for (int kc = 0; kc < 8; ++kc) {
#pragma unroll
        for (int nsi = 0; nsi < 4; ++nsi) {
          size_t bo = (((size_t)(e * 4 + nsi)) * 8 + kc) * 512 + l * 8;
          bf16x8 bh = *(const bf16x8*)(E3H + bo);
          acc[nsi] = MFMA(ah[kc], bh, acc[nsi], 0, 0, 0);
          acc[nsi] = MFMA(al[kc], bh, acc[nsi], 0, 0, 0);
        }
      }
#pragma unroll
      for (int nsi = 0; nsi < 4; ++nsi)
#pragma unroll
        for (int r = 0; r < 4; ++r)
          U.g3.p3s[e][quad * 4 + r][nsi * 16 + c] = acc[nsi][r];
    }
    __syncthreads();
#pragma unroll
    for (int i = 0; i < 4; ++i) {
      int idx = t + i * 256;             // 1024 outputs: [16 rows][64 cols]
      int row = idx >> 6, col = idx & 63;
      float s = 0.f;
#pragma unroll
      for (int e2 = 0; e2 < 8; ++e2)
        s = fmaf(bcL[row][e2], U.g3.p3s[e2][row][col] + U.g3.eb3L[e2][col], s);
      if (col < DOUT) out[(size_t)(R0 + row) * DOUT + col] = s;
    }
  }
}

extern "C" void kernel_launch(void* const* d_in, const int* in_sizes, int n_in,
                              void* d_out, int out_size, void* d_ws, size_t ws_size,
                              hipStream_t stream) {
  const float* x      = (const float*)d_in[0];
  const float* w1     = (const float*)d_in[1];
  const float* b1     = (const float*)d_in[2];
  const float* gamma1 = (const float*)d_in[3];
  const float* beta1  = (const float*)d_in[4];
  const float* w2     = (const float*)d_in[5];
  const float* b2     = (const float*)d_in[6];
  const float* gamma2 = (const float*)d_in[7];
  const float* beta2  = (const float*)d_in[8];
  const float* gw1    = (const float*)d_in[9];
  const float* gb1    = (const float*)d_in[10];
  const float* gw2    = (const float*)d_in[11];
  const float* gb2    = (const float*)d_in[12];
  const float* gw3    = (const float*)d_in[13];
  const float* gb3    = (const float*)d_in[14];
  const float* ew1    = (const float*)d_in[15];
  const float* eb1    = (const float*)d_in[16];
  const float* ew2    = (const float*)d_in[17];
  const float* eb2    = (const float*)d_in[18];
  const float* ew3    = (const float*)d_in[19];
  const float* eb3    = (const float*)d_in[20];
  float* wsf  = (float*)d_ws;
  float* outp = (float*)d_out;

  k_prep_enc1<<<576, 256, 0, stream>>>(x, w1, b1, ew1, ew2, ew3, wsf);
  k_rest<<<256, 256, 0, stream>>>(gamma1, beta1, w2, b2, gamma2, beta2,
                                  gw1, gb1, gw2, gb2, gw3, gb3,
                                  eb1, eb2, eb3, wsf, outp);
}

// Round 7
// 151.179 us; speedup vs baseline: 1.3149x; 1.0576x over previous
//
#include <hip/hip_runtime.h>
#include <math.h>

// Network_22892175688023 — round 17: mega64 — ONE 64-block tree barrier. 2 stages.
//   K1 k_prep_enc1 : E-planes + Xs frags + enc L1 VALU + zero barrier (576 blk) [unchanged]
//   K2 k_mega      : 64 blk x 512 thr (1 block/CU on 64 CUs):
//                    P0 E-plane L2-prefetch (slice blk>>3) || P1 enc2 (own 16 rows,
//                       hb2 kept in LDS, slots2 write-through) -> gbar64 (ONLY grid sync)
//                    P2 slots2 reduce + gate + gen1+comb1 -> A1 frags LDS
//                    P3 gen2+comb2 -> A2 frags LDS
//                    P4 gen3 (8 waves = experts) + reduce -> out
//   Rationale: all cross-block deps collapse to the BN2-stats reduce; everything
//   else is per-msub block-local. R11 mega was latency-bound on cold E-planes
//   (10 MB @ 222 GB/s) -> prefetch warms L2 under enc2. 64-arrival tree barrier
//   ~1-2us vs 15-20us for 256-block barriers. Numerics verbatim (absmax 3.9e-3).

#define DIN 103
#define NE  8
#define HH  256
#define DOUT 51
#define EPSBN 1e-5f

typedef __attribute__((ext_vector_type(8))) short bf16x8;
typedef __attribute__((ext_vector_type(4))) float f32x4;
typedef __attribute__((ext_vector_type(8))) unsigned short us8;
typedef unsigned short ushort_t;

__device__ __forceinline__ float eluf(float v) { return v > 0.f ? v : (expf(v) - 1.f); }
__device__ __forceinline__ unsigned short bf16h(float f) {
  unsigned u = __float_as_uint(f);
  u += 0x7FFFu + ((u >> 16) & 1u);
  return (unsigned short)(u >> 16);
}
__device__ __forceinline__ float bf16f(unsigned short h) { return __uint_as_float(((unsigned)h) << 16); }
__device__ __forceinline__ void split_bf16(float v, unsigned short& h, unsigned short& l) {
  h = bf16h(v);
  l = bf16h(v - bf16f(h));
}
#define MFMA __builtin_amdgcn_mfma_f32_16x16x32_bf16

// relaxed agent-scope coherent access helpers (no cache-maintenance ops)
__device__ __forceinline__ void stA(float* p, float v) {
  __hip_atomic_store(p, v, __ATOMIC_RELAXED, __HIP_MEMORY_SCOPE_AGENT);
}
__device__ __forceinline__ float ldA(const float* p) {
  return __hip_atomic_load((float*)p, __ATOMIC_RELAXED, __HIP_MEMORY_SCOPE_AGENT);
}
__device__ __forceinline__ void stAu(unsigned* p, unsigned v) {
  __hip_atomic_store(p, v, __ATOMIC_RELAXED, __HIP_MEMORY_SCOPE_AGENT);
}
__device__ __forceinline__ unsigned ldAu(const unsigned* p) {
  return __hip_atomic_load((unsigned*)p, __ATOMIC_RELAXED, __HIP_MEMORY_SCOPE_AGENT);
}

// ---- ws layout (float offsets) ----
#define O_SLOTS1 0        // [64][128]
#define O_SLOTS2 8192     // [64][64]
#define O_H1RAW  20480    // [1024][64]
#define O_XSH    118784   // [64 msub][4 kc][512] sh
#define O_XSL    184320
#define O_E1H    258048   // [8 e][16 ns][4 kc][512] sh
#define O_E1L    389120
#define O_E2H    520192   // [8 e][16 ns][8 kc][512] sh  (hi only)
#define O_E3H    782336   // [8 e][4 ns][8 kc][512] sh   (hi only)
#define O_ESPAN  589824   // floats: E1H..E3H end (contiguous 2.25 MB)
#define O_BAR    1372160  // 1024-dword tree-barrier region (zeroed by K1)

// 8x8 tree barrier for 64 blocks; region: grp[i]@i*32 (i<8), root@256,
// rel[j]@288+j*32 (j<8). Used exactly once per launch.
__device__ __forceinline__ void gbar64(unsigned* base, int blk) {
  asm volatile("s_waitcnt vmcnt(0)" ::: "memory");
  __syncthreads();
  if (threadIdx.x == 0) {
    unsigned a = __hip_atomic_fetch_add(base + (blk >> 3) * 32, 1u,
                                        __ATOMIC_RELAXED, __HIP_MEMORY_SCOPE_AGENT);
    if (a == 7u) {
      unsigned r = __hip_atomic_fetch_add(base + 256, 1u,
                                          __ATOMIC_RELAXED, __HIP_MEMORY_SCOPE_AGENT);
      if (r == 7u) {
#pragma unroll
        for (int j = 0; j < 8; ++j) stAu(base + 288 + j * 32, 1u);
      }
    }
    while (ldAu(base + 288 + (blk & 7) * 32) == 0u)
      __builtin_amdgcn_s_sleep(2);
  }
  __syncthreads();
}

// ================= K1: prep planes + Xs frags + enc L1 (VALU) =================
// blocks: E2 0..255 | E1 256..383 | E3 384..447 | Xs 448..511 | enc1 512..575
__global__ __launch_bounds__(256) void k_prep_enc1(
    const float* __restrict__ x, const float* __restrict__ w1, const float* __restrict__ b1,
    const float* __restrict__ ew1, const float* __restrict__ ew2, const float* __restrict__ ew3,
    float* __restrict__ ws) {
  __shared__ union {
    float tile[32][65];
    float xt[16][104];
    struct { float w1L[64 * DIN]; float xr[16][104]; float hb[16][64]; } e1;
  } sm;
  int bk = blockIdx.x, t = threadIdx.x;
  int l2 = t & 63, c = l2 & 15, q = l2 >> 4;
  if (bk == 0) {   // zero barrier region (1024 dwords)
    unsigned* bz = (unsigned*)(ws + O_BAR);
#pragma unroll
    for (int i = 0; i < 4; ++i) bz[t + i * 256] = 0u;
  }

  if (bk < 256) {          // ---- E2: K=256, N=256, hi only ----
    int nh = bk & 3, kc = (bk >> 2) & 7, e = bk >> 5;
    int k0 = kc * 32, n0 = nh * 64;
#pragma unroll
    for (int i = 0; i < 8; ++i) {
      int kl = (t >> 6) + i * 4;
      sm.tile[kl][t & 63] = ew2[((size_t)e * HH + k0 + kl) * HH + n0 + (t & 63)];
    }
    __syncthreads();
    int nsl = t >> 6;
    us8 H8;
#pragma unroll
    for (int j = 0; j < 8; ++j) H8[j] = bf16h(sm.tile[q * 8 + j][nsl * 16 + c]);
    size_t dst = (((size_t)(e * 16 + nh * 4 + nsl)) * 8 + kc) * 512 + l2 * 8;
    *(us8*)((ushort_t*)(ws + O_E2H) + dst) = H8;
  } else if (bk < 384) {   // ---- E1: K=103->128, N=256, hi+lo ----
    int b2 = bk - 256;
    int nh = b2 & 3, kc = (b2 >> 2) & 3, e = b2 >> 4;
    int k0 = kc * 32, n0 = nh * 64;
#pragma unroll
    for (int i = 0; i < 8; ++i) {
      int kl = (t >> 6) + i * 4;
      int k = k0 + kl;
      sm.tile[kl][t & 63] = (k < DIN) ? ew1[((size_t)e * DIN + k) * HH + n0 + (t & 63)] : 0.f;
    }
    __syncthreads();
    int nsl = t >> 6;
    us8 H8, L8;
#pragma unroll
    for (int j = 0; j < 8; ++j) {
      unsigned short h, lo; split_bf16(sm.tile[q * 8 + j][nsl * 16 + c], h, lo);
      H8[j] = h; L8[j] = lo;
    }
    size_t dst = (((size_t)(e * 16 + nh * 4 + nsl)) * 4 + kc) * 512 + l2 * 8;
    *(us8*)((ushort_t*)(ws + O_E1H) + dst) = H8;
    *(us8*)((ushort_t*)(ws + O_E1L) + dst) = L8;
  } else if (bk < 448) {   // ---- E3: K=256, N=51->64, hi only ----
    int b2 = bk - 384;
    int kc = b2 & 7, e = b2 >> 3;
    int k0 = kc * 32;
#pragma unroll
    for (int i = 0; i < 8; ++i) {
      int kl = (t >> 6) + i * 4;
      int n = t & 63;
      sm.tile[kl][n] = (n < DOUT) ? ew3[((size_t)e * HH + k0 + kl) * DOUT + n] : 0.f;
    }
    __syncthreads();
    int nsl = t >> 6;
    us8 H8;
#pragma unroll
    for (int j = 0; j < 8; ++j) H8[j] = bf16h(sm.tile[q * 8 + j][nsl * 16 + c]);
    size_t dst = (((size_t)(e * 4 + nsl)) * 8 + kc) * 512 + l2 * 8;
    *(us8*)((ushort_t*)(ws + O_E3H) + dst) = H8;
  } else if (bk < 512) {   // ---- Xs: A-fragments of scaled x, 16 rows/block, hi+lo ----
    int msub = bk - 448;
    for (int i = t; i < 16 * 104; i += 256) {
      int b = i / 104, k = i - b * 104;
      float v = 0.f;
      if (k < DIN) { v = x[(size_t)(msub * 16 + b) * DIN + k]; if (k >= 100) v *= 100.f; }
      sm.xt[b][k] = v;
    }
    __syncthreads();
    int kc = t >> 6;
    int m = c;
    us8 H8, L8;
#pragma unroll
    for (int j = 0; j < 8; ++j) {
      int k = kc * 32 + q * 8 + j;
      float v = (k < 104) ? sm.xt[m][k] : 0.f;
      unsigned short h, lo; split_bf16(v, h, lo);
      H8[j] = h; L8[j] = lo;
    }
    size_t dst = ((size_t)msub * 4 + kc) * 512 + l2 * 8;
    *(us8*)((ushort_t*)(ws + O_XSH) + dst) = H8;
    *(us8*)((ushort_t*)(ws + O_XSL) + dst) = L8;
  } else {                 // ---- enc L1 (VALU): 16 rows/block ----
    float* slots1 = ws + O_SLOTS1;
    float* h1raw  = ws + O_H1RAW;
    int bkl = bk - 512;
    int r0 = bkl * 16;
    for (int i = t; i < 64 * DIN; i += 256) sm.e1.w1L[i] = w1[i];
    for (int i = t; i < 16 * 104; i += 256) {
      int r = i / 104, c2 = i - r * 104;
      float v = 0.f;
      if (c2 < DIN) { v = x[(size_t)(r0 + r) * DIN + c2]; if (c2 >= 100) v *= 100.f; }
      sm.e1.xr[r][c2] = v;
    }
    __syncthreads();
#pragma unroll
    for (int i = 0; i < 4; ++i) {
      int idx = t + i * 256;
      int r = idx >> 6, j = idx & 63;
      float acc = b1[j];
      for (int k = 0; k < DIN; ++k) acc = fmaf(sm.e1.xr[r][k], sm.e1.w1L[j * DIN + k], acc);
      sm.e1.hb[r][j] = acc;
      h1raw[(size_t)(r0 + r) * 64 + j] = acc;
    }
    __syncthreads();
    if (t < 64) {
      float s = 0.f, qq = 0.f;
      for (int r = 0; r < 16; ++r) { float v = sm.e1.hb[r][t]; s += v; qq += v * v; }
      slots1[bkl * 128 + t] = s;
      slots1[bkl * 128 + 64 + t] = qq;
    }
  }
}

// ================= K2: k_mega — enc2 -> gbar64 -> gate+gen1 -> gen2 -> gen3 =================
__global__ __launch_bounds__(512) void k_mega(
    const float* __restrict__ gamma1, const float* __restrict__ beta1,
    const float* __restrict__ w2, const float* __restrict__ b2,
    const float* __restrict__ gamma2, const float* __restrict__ beta2,
    const float* __restrict__ gw1, const float* __restrict__ gb1,
    const float* __restrict__ gw2, const float* __restrict__ gb2,
    const float* __restrict__ gw3, const float* __restrict__ gb3,
    const float* __restrict__ eb1, const float* __restrict__ eb2,
    const float* __restrict__ eb3,
    float* __restrict__ ws, float* __restrict__ out) {
  __shared__ union {
    struct { float w2T[64 * 33]; float red[128]; float sc1[64], sh1[64];
             float h1b[16][64]; } enc2;
    struct { float gw1L[64 * 33]; float gw2L[64 * 65]; float gw3L[8 * 65];
             float gb1L[64], gb2L[64], gb3L[8];
             float red2[64], sc2[32], sh2[32];
             float lat[16][32]; float g1[16][64], g2[16][64]; } gate;
    struct { float hT[256][17]; float eb[2048]; } comb;
    struct { float p3s[8][16][64]; float eb3L[8][64]; } g3;
  } U;
  __shared__ float hb2s[16][32];     // enc L2 pre-BN output, persists P1 -> P2
  __shared__ us8 aHv[512], aLv[512]; // A-fragments [kc][l2], reused A1 -> A2
  __shared__ float bcL[16][8];       // persists P2 -> P4

  const int blk = blockIdx.x, t = threadIdx.x;
  const int wv = t >> 6, l = t & 63, c = l & 15, quad = l >> 4;
  const int R0 = blk * 16;
  unsigned* bar = (unsigned*)(ws + O_BAR);
  const ushort_t* XsH = (const ushort_t*)(ws + O_XSH);
  const ushort_t* XsL = (const ushort_t*)(ws + O_XSL);
  const ushort_t* E1H = (const ushort_t*)(ws + O_E1H);
  const ushort_t* E1L = (const ushort_t*)(ws + O_E1L);
  const ushort_t* E2H = (const ushort_t*)(ws + O_E2H);
  const ushort_t* E3H = (const ushort_t*)(ws + O_E3H);

  // early A-fragment loads (K1 output, plain cached)
  bf16x8 a1h[4], a1l[4];
#pragma unroll
  for (int kc = 0; kc < 4; ++kc) {
    a1h[kc] = *(const bf16x8*)(XsH + ((size_t)blk * 4 + kc) * 512 + l * 8);
    a1l[kc] = *(const bf16x8*)(XsL + ((size_t)blk * 4 + kc) * 512 + l * 8);
  }

  // ---------- P0: E-plane L2 prefetch (slice blk>>3 so each XCD's 8 blocks
  //            cover the full 2.25 MB) — overlaps P1 enc2 + barrier ----------
  {
    const int slice = blk >> 3;                 // 0..7
    const float4* src = (const float4*)(ws + O_E1H);
    float ka = 0.f;
#pragma unroll
    for (int i = 0; i < 36; ++i) {
      float4 v = src[(size_t)slice * 18432 + (size_t)i * 512 + t];  // 73728 floats/slice
      ka += v.x + v.y + v.z + v.w;
    }
    asm volatile("" :: "v"(ka));                // keep loads alive
  }

  // ---------- P1: enc2 for own 16 rows (hb2 stays in LDS; slots2 write-through) ----------
  {
    const float* slots1 = ws + O_SLOTS1;
    float* slots2 = ws + O_SLOTS2;
    const float* h1raw = ws + O_H1RAW;
    for (int i = t; i < 2048; i += 512) { int j = i >> 6, k = i & 63; U.enc2.w2T[k * 33 + j] = w2[i]; }
    if (t < 128) {
      float s = 0.f;
      for (int b = 0; b < 64; ++b) s += slots1[b * 128 + t];
      U.enc2.red[t] = s;
    }
    __syncthreads();
    if (t < 64) {
      float mm = U.enc2.red[t] * (1.f / 1024.f);
      float v = U.enc2.red[64 + t] * (1.f / 1024.f) - mm * mm;
      float sc = gamma1[t] * rsqrtf(v + EPSBN);
      U.enc2.sc1[t] = sc; U.enc2.sh1[t] = beta1[t] - mm * sc;
    }
    __syncthreads();
#pragma unroll
    for (int i = 0; i < 2; ++i) {
      int idx = t + i * 512;
      int r = idx >> 6, k = idx & 63;
      U.enc2.h1b[r][k] = fmaxf(fmaf(h1raw[(size_t)(R0 + r) * 64 + k], U.enc2.sc1[k], U.enc2.sh1[k]), 0.f);
    }
    __syncthreads();
    {
      int r = t >> 5, j = t & 31;              // 512 outputs = 16 x 32
      float acc = b2[j];
      for (int k = 0; k < 64; ++k) acc = fmaf(U.enc2.h1b[r][k], U.enc2.w2T[k * 33 + j], acc);
      hb2s[r][j] = acc;
    }
    __syncthreads();
    if (t < 32) {
      float s = 0.f, q = 0.f;
      for (int r = 0; r < 16; ++r) { float v = hb2s[r][t]; s += v; q += v * v; }
      stA(slots2 + blk * 64 + t, s);
      stA(slots2 + blk * 64 + 32 + t, q);
    }
  }
  gbar64(bar, blk);    // the ONLY grid sync

  // ---------- P2: gate (own rows, from LDS hb2s) + gen1+comb1 -> A1 frags ----------
  {
    const float* slots2 = ws + O_SLOTS2;
    for (int i = t; i < 2048; i += 512) { int j = i >> 5, k = i & 31; U.gate.gw1L[j * 33 + k] = gw1[i]; }
    for (int i = t; i < 4096; i += 512) { int j = i >> 6, k = i & 63; U.gate.gw2L[j * 65 + k] = gw2[i]; }
    { int j = t >> 6, k = t & 63; U.gate.gw3L[j * 65 + k] = gw3[t]; }
    if (t < 64) { U.gate.gb1L[t] = gb1[t]; U.gate.gb2L[t] = gb2[t]; }
    if (t < 8) U.gate.gb3L[t] = gb3[t];
    if (t < 64) {
      float vvv[64];
#pragma unroll
      for (int b = 0; b < 64; ++b) vvv[b] = ldA(slots2 + b * 64 + t);
      float s = 0.f;
#pragma unroll
      for (int b = 0; b < 64; ++b) s += vvv[b];            // same order -> bit-identical
      U.gate.red2[t] = s;
    }
    __syncthreads();
    if (t < 32) {
      float mm = U.gate.red2[t] * (1.f / 1024.f);
      float v = U.gate.red2[32 + t] * (1.f / 1024.f) - mm * mm;
      float sc = gamma2[t] * rsqrtf(v + EPSBN);
      U.gate.sc2[t] = sc; U.gate.sh2[t] = beta2[t] - mm * sc;
    }
    __syncthreads();
    { int r = t >> 5, cc = t & 31;
      U.gate.lat[r][cc] = fmaxf(fmaf(hb2s[r][cc], U.gate.sc2[cc], U.gate.sh2[cc]), 0.f); }
    __syncthreads();
#pragma unroll
    for (int rr = 0; rr < 2; ++rr) {
      int r = wv * 2 + rr;
      float a1 = U.gate.gb1L[l];
      for (int k = 0; k < 32; ++k) a1 = fmaf(U.gate.gw1L[l * 33 + k], U.gate.lat[r][k], a1);
      U.gate.g1[r][l] = eluf(a1);
    }
    __syncthreads();
#pragma unroll
    for (int rr = 0; rr < 2; ++rr) {
      int r = wv * 2 + rr;
      float a2 = U.gate.gb2L[l];
      for (int k = 0; k < 64; ++k) a2 = fmaf(U.gate.gw2L[l * 65 + k], U.gate.g1[r][k], a2);
      U.gate.g2[r][l] = eluf(a2);
    }
    __syncthreads();
#pragma unroll
    for (int rr = 0; rr < 2; ++rr) {
      int r = wv * 2 + rr;
      if (l < 8) {
        float a3 = U.gate.gb3L[l];
        for (int k = 0; k < 64; ++k) a3 = fmaf(U.gate.gw3L[l * 65 + k], U.gate.g2[r][k], a3);
        float mx = a3;
        mx = fmaxf(mx, __shfl_xor(mx, 1));
        mx = fmaxf(mx, __shfl_xor(mx, 2));
        mx = fmaxf(mx, __shfl_xor(mx, 4));
        float p = expf(a3 - mx);
        float sp = p;
        sp += __shfl_xor(sp, 1); sp += __shfl_xor(sp, 2); sp += __shfl_xor(sp, 4);
        bcL[r][l] = p / sp;
      }
    }
    __syncthreads();   // gate done; union reused below

    // gen1 + comb1 (8 waves x 2 ns each)
    for (int i = t; i < 2048; i += 512) U.comb.eb[i] = eb1[i];
    __syncthreads();
    {
      f32x4 blend[2] = {};
#pragma unroll
      for (int e = 0; e < NE; ++e) {
        float bcv[4];
#pragma unroll
        for (int r = 0; r < 4; ++r) bcv[r] = bcL[quad * 4 + r][e];
#pragma unroll
        for (int nsi = 0; nsi < 2; ++nsi) {
          int ns = wv * 2 + nsi;
          f32x4 acc = {};
#pragma unroll
          for (int kc = 0; kc < 4; ++kc) {
            size_t bo = (((size_t)(e * 16 + ns)) * 4 + kc) * 512 + l * 8;
            bf16x8 bh = *(const bf16x8*)(E1H + bo);
            bf16x8 bl = *(const bf16x8*)(E1L + bo);
            acc = MFMA(a1h[kc], bh, acc, 0, 0, 0);
            acc = MFMA(a1l[kc], bh, acc, 0, 0, 0);
            acc = MFMA(a1h[kc], bl, acc, 0, 0, 0);
          }
          float ebv = U.comb.eb[e * HH + ns * 16 + c];
#pragma unroll
          for (int r = 0; r < 4; ++r) blend[nsi][r] = fmaf(bcv[r], acc[r] + ebv, blend[nsi][r]);
        }
      }
#pragma unroll
      for (int nsi = 0; nsi < 2; ++nsi) {
        int col = (wv * 2 + nsi) * 16 + c;
#pragma unroll
        for (int r = 0; r < 4; ++r) U.comb.hT[col][quad * 4 + r] = eluf(blend[nsi][r]);
      }
    }
    __syncthreads();
    {   // repack hT -> A1 fragments (hi+lo), t = kc*64 + l2
      int l2 = t & 63, row = l2 & 15, k0 = (t >> 6) * 32 + (l2 >> 4) * 8;
      us8 H, L;
#pragma unroll
      for (int j = 0; j < 8; ++j) {
        unsigned short h, lo; split_bf16(U.comb.hT[k0 + j][row], h, lo);
        H[j] = h; L[j] = lo;
      }
      aHv[t] = H; aLv[t] = L;
    }
    __syncthreads();
  }

  // ---------- P3: gen2 + comb2 -> A2 frags in LDS ----------
  {
    for (int i = t; i < 2048; i += 512) U.comb.eb[i] = eb2[i];
    bf16x8 a2h[8], a2l[8];          // hoist A1 frags from LDS
#pragma unroll
    for (int kc = 0; kc < 8; ++kc) {
      a2h[kc] = *(const bf16x8*)&aHv[kc * 64 + l];
      a2l[kc] = *(const bf16x8*)&aLv[kc * 64 + l];
    }
    __syncthreads();
    {
      f32x4 blend[2] = {};
#pragma unroll
      for (int e = 0; e < NE; ++e) {
        float bcv[4];
#pragma unroll
        for (int r = 0; r < 4; ++r) bcv[r] = bcL[quad * 4 + r][e];
#pragma unroll
        for (int nsi = 0; nsi < 2; ++nsi) {
          int ns = wv * 2 + nsi;
          f32x4 acc = {};
#pragma unroll
          for (int kc = 0; kc < 8; ++kc) {
            size_t bo = (((size_t)(e * 16 + ns)) * 8 + kc) * 512 + l * 8;
            bf16x8 bh = *(const bf16x8*)(E2H + bo);
            acc = MFMA(a2h[kc], bh, acc, 0, 0, 0);
            acc = MFMA(a2l[kc], bh, acc, 0, 0, 0);
          }
          float ebv = U.comb.eb[e * HH + ns * 16 + c];
#pragma unroll
          for (int r = 0; r < 4; ++r) blend[nsi][r] = fmaf(bcv[r], acc[r] + ebv, blend[nsi][r]);
        }
      }
#pragma unroll
      for (int nsi = 0; nsi < 2; ++nsi) {
        int col = (wv * 2 + nsi) * 16 + c;
#pragma unroll
        for (int r = 0; r < 4; ++r) U.comb.hT[col][quad * 4 + r] = eluf(blend[nsi][r]);
      }
    }
    __syncthreads();
    {   // repack hT -> A2 fragments (overwrites A1; reads were from registers)
      int l2 = t & 63, row = l2 & 15, k0 = (t >> 6) * 32 + (l2 >> 4) * 8;
      us8 H, L;
#pragma unroll
      for (int j = 0; j < 8; ++j) {
        unsigned short h, lo; split_bf16(U.comb.hT[k0 + j][row], h, lo);
        H[j] = h; L[j] = lo;
      }
      aHv[t] = H; aLv[t] = L;
    }
    __syncthreads();
  }

  // ---------- P4: gen3 (wave = expert) + cross-expert reduce -> out ----------
  {
    { int e = t >> 6, n = t & 63; U.g3.eb3L[e][n] = (n < DOUT) ? eb3[e * DOUT + n] : 0.f; }
    const int e = wv;
    f32x4 acc[4] = {};
#pragma unroll
    for (int kc = 0; kc < 8; ++kc) {
      bf16x8 ah = *(const bf16x8*)&aHv[kc * 64 + l];
      bf16x8 al = *(const bf16x8*)&aLv[kc * 64 + l];
#pragma unroll
      for (int nsi = 0; nsi < 4; ++nsi) {
        size_t bo = (((size_t)(e * 4 + nsi)) * 8 + kc) * 512 + l * 8;
        bf16x8 bh = *(const bf16x8*)(E3H + bo);
        acc[nsi] = MFMA(ah, bh, acc[nsi], 0, 0, 0);
        acc[nsi] = MFMA(al, bh, acc[nsi], 0, 0, 0);
      }
    }
#pragma unroll
    for (int nsi = 0; nsi < 4; ++nsi)
#pragma unroll
      for (int r = 0; r < 4; ++r)
        U.g3.p3s[e][quad * 4 + r][nsi * 16 + c] = acc[nsi][r];
    __syncthreads();
#pragma unroll
    for (int i = 0; i < 2; ++i) {
      int idx = t + i * 512;             // 1024 outputs: [16 rows][64 cols]
      int row = idx >> 6, col = idx & 63;
      float s = 0.f;
#pragma unroll
      for (int e2 = 0; e2 < 8; ++e2)
        s = fmaf(bcL[row][e2], U.g3.p3s[e2][row][col] + U.g3.eb3L[e2][col], s);
      if (col < DOUT) out[(size_t)(R0 + row) * DOUT + col] = s;
    }
  }
}

extern "C" void kernel_launch(void* const* d_in, const int* in_sizes, int n_in,
                              void* d_out, int out_size, void* d_ws, size_t ws_size,
                              hipStream_t stream) {
  const float* x      = (const float*)d_in[0];
  const float* w1     = (const float*)d_in[1];
  const float* b1     = (const float*)d_in[2];
  const float* gamma1 = (const float*)d_in[3];
  const float* beta1  = (const float*)d_in[4];
  const float* w2     = (const float*)d_in[5];
  const float* b2     = (const float*)d_in[6];
  const float* gamma2 = (const float*)d_in[7];
  const float* beta2  = (const float*)d_in[8];
  const float* gw1    = (const float*)d_in[9];
  const float* gb1    = (const float*)d_in[10];
  const float* gw2    = (const float*)d_in[11];
  const float* gb2    = (const float*)d_in[12];
  const float* gw3    = (const float*)d_in[13];
  const float* gb3    = (const float*)d_in[14];
  const float* ew1    = (const float*)d_in[15];
  const float* eb1    = (const float*)d_in[16];
  const float* ew2    = (const float*)d_in[17];
  const float* eb2    = (const float*)d_in[18];
  const float* ew3    = (const float*)d_in[19];
  const float* eb3    = (const float*)d_in[20];
  float* wsf  = (float*)d_ws;
  float* outp = (float*)d_out;

  k_prep_enc1<<<576, 256, 0, stream>>>(x, w1, b1, ew1, ew2, ew3, wsf);
  k_mega<<<64, 512, 0, stream>>>(gamma1, beta1, w2, b2, gamma2, beta2,
                                 gw1, gb1, gw2, gb2, gw3, gb3,
                                 eb1, eb2, eb3, wsf, outp);
}

// Round 8
// 141.930 us; speedup vs baseline: 1.4006x; 1.0652x over previous
//
#include <hip/hip_runtime.h>
#include <math.h>

// Network_22892175688023 — round 18: mega64 @ 1024 threads (16 waves). 2 stages.
//   R17 post-mortem: gen phases ~43us invariant across 4 structures = latency-bound
//   global reads with only 8 waves of MLP per CU. Fix: 16 waves/block (1024 thr),
//   each wave owns ONE ns strip in P2/P3 (was two). Per-(e,ns) MFMA chains verbatim
//   -> bit-identical numerics (absmax 3.9e-3). P3 un-hoists A-frags (LDS re-read in
//   e-loop) to hold VGPR <= 128 (16 waves = 4/SIMD). P4 unchanged: 8 waves = experts.
//   K1 k_prep_enc1 unchanged.

#define DIN 103
#define NE  8
#define HH  256
#define DOUT 51
#define EPSBN 1e-5f

typedef __attribute__((ext_vector_type(8))) short bf16x8;
typedef __attribute__((ext_vector_type(4))) float f32x4;
typedef __attribute__((ext_vector_type(8))) unsigned short us8;
typedef unsigned short ushort_t;

__device__ __forceinline__ float eluf(float v) { return v > 0.f ? v : (expf(v) - 1.f); }
__device__ __forceinline__ unsigned short bf16h(float f) {
  unsigned u = __float_as_uint(f);
  u += 0x7FFFu + ((u >> 16) & 1u);
  return (unsigned short)(u >> 16);
}
__device__ __forceinline__ float bf16f(unsigned short h) { return __uint_as_float(((unsigned)h) << 16); }
__device__ __forceinline__ void split_bf16(float v, unsigned short& h, unsigned short& l) {
  h = bf16h(v);
  l = bf16h(v - bf16f(h));
}
#define MFMA __builtin_amdgcn_mfma_f32_16x16x32_bf16

// relaxed agent-scope coherent access helpers (no cache-maintenance ops)
__device__ __forceinline__ void stA(float* p, float v) {
  __hip_atomic_store(p, v, __ATOMIC_RELAXED, __HIP_MEMORY_SCOPE_AGENT);
}
__device__ __forceinline__ float ldA(const float* p) {
  return __hip_atomic_load((float*)p, __ATOMIC_RELAXED, __HIP_MEMORY_SCOPE_AGENT);
}
__device__ __forceinline__ void stAu(unsigned* p, unsigned v) {
  __hip_atomic_store(p, v, __ATOMIC_RELAXED, __HIP_MEMORY_SCOPE_AGENT);
}
__device__ __forceinline__ unsigned ldAu(const unsigned* p) {
  return __hip_atomic_load((unsigned*)p, __ATOMIC_RELAXED, __HIP_MEMORY_SCOPE_AGENT);
}

// ---- ws layout (float offsets) ----
#define O_SLOTS1 0        // [64][128]
#define O_SLOTS2 8192     // [64][64]
#define O_H1RAW  20480    // [1024][64]
#define O_XSH    118784   // [64 msub][4 kc][512] sh
#define O_XSL    184320
#define O_E1H    258048   // [8 e][16 ns][4 kc][512] sh
#define O_E1L    389120
#define O_E2H    520192   // [8 e][16 ns][8 kc][512] sh  (hi only)
#define O_E3H    782336   // [8 e][4 ns][8 kc][512] sh   (hi only)
#define O_BAR    1372160  // 1024-dword tree-barrier region (zeroed by K1)

// 8x8 tree barrier for 64 blocks; region: grp[i]@i*32 (i<8), root@256,
// rel[j]@288+j*32 (j<8). Used exactly once per launch.
__device__ __forceinline__ void gbar64(unsigned* base, int blk) {
  asm volatile("s_waitcnt vmcnt(0)" ::: "memory");
  __syncthreads();
  if (threadIdx.x == 0) {
    unsigned a = __hip_atomic_fetch_add(base + (blk >> 3) * 32, 1u,
                                        __ATOMIC_RELAXED, __HIP_MEMORY_SCOPE_AGENT);
    if (a == 7u) {
      unsigned r = __hip_atomic_fetch_add(base + 256, 1u,
                                          __ATOMIC_RELAXED, __HIP_MEMORY_SCOPE_AGENT);
      if (r == 7u) {
#pragma unroll
        for (int j = 0; j < 8; ++j) stAu(base + 288 + j * 32, 1u);
      }
    }
    while (ldAu(base + 288 + (blk & 7) * 32) == 0u)
      __builtin_amdgcn_s_sleep(2);
  }
  __syncthreads();
}

// ================= K1: prep planes + Xs frags + enc L1 (VALU) =================
// blocks: E2 0..255 | E1 256..383 | E3 384..447 | Xs 448..511 | enc1 512..575
__global__ __launch_bounds__(256) void k_prep_enc1(
    const float* __restrict__ x, const float* __restrict__ w1, const float* __restrict__ b1,
    const float* __restrict__ ew1, const float* __restrict__ ew2, const float* __restrict__ ew3,
    float* __restrict__ ws) {
  __shared__ union {
    float tile[32][65];
    float xt[16][104];
    struct { float w1L[64 * DIN]; float xr[16][104]; float hb[16][64]; } e1;
  } sm;
  int bk = blockIdx.x, t = threadIdx.x;
  int l2 = t & 63, c = l2 & 15, q = l2 >> 4;
  if (bk == 0) {   // zero barrier region (1024 dwords)
    unsigned* bz = (unsigned*)(ws + O_BAR);
#pragma unroll
    for (int i = 0; i < 4; ++i) bz[t + i * 256] = 0u;
  }

  if (bk < 256) {          // ---- E2: K=256, N=256, hi only ----
    int nh = bk & 3, kc = (bk >> 2) & 7, e = bk >> 5;
    int k0 = kc * 32, n0 = nh * 64;
#pragma unroll
    for (int i = 0; i < 8; ++i) {
      int kl = (t >> 6) + i * 4;
      sm.tile[kl][t & 63] = ew2[((size_t)e * HH + k0 + kl) * HH + n0 + (t & 63)];
    }
    __syncthreads();
    int nsl = t >> 6;
    us8 H8;
#pragma unroll
    for (int j = 0; j < 8; ++j) H8[j] = bf16h(sm.tile[q * 8 + j][nsl * 16 + c]);
    size_t dst = (((size_t)(e * 16 + nh * 4 + nsl)) * 8 + kc) * 512 + l2 * 8;
    *(us8*)((ushort_t*)(ws + O_E2H) + dst) = H8;
  } else if (bk < 384) {   // ---- E1: K=103->128, N=256, hi+lo ----
    int b2 = bk - 256;
    int nh = b2 & 3, kc = (b2 >> 2) & 3, e = b2 >> 4;
    int k0 = kc * 32, n0 = nh * 64;
#pragma unroll
    for (int i = 0; i < 8; ++i) {
      int kl = (t >> 6) + i * 4;
      int k = k0 + kl;
      sm.tile[kl][t & 63] = (k < DIN) ? ew1[((size_t)e * DIN + k) * HH + n0 + (t & 63)] : 0.f;
    }
    __syncthreads();
    int nsl = t >> 6;
    us8 H8, L8;
#pragma unroll
    for (int j = 0; j < 8; ++j) {
      unsigned short h, lo; split_bf16(sm.tile[q * 8 + j][nsl * 16 + c], h, lo);
      H8[j] = h; L8[j] = lo;
    }
    size_t dst = (((size_t)(e * 16 + nh * 4 + nsl)) * 4 + kc) * 512 + l2 * 8;
    *(us8*)((ushort_t*)(ws + O_E1H) + dst) = H8;
    *(us8*)((ushort_t*)(ws + O_E1L) + dst) = L8;
  } else if (bk < 448) {   // ---- E3: K=256, N=51->64, hi only ----
    int b2 = bk - 384;
    int kc = b2 & 7, e = b2 >> 3;
    int k0 = kc * 32;
#pragma unroll
    for (int i = 0; i < 8; ++i) {
      int kl = (t >> 6) + i * 4;
      int n = t & 63;
      sm.tile[kl][n] = (n < DOUT) ? ew3[((size_t)e * HH + k0 + kl) * DOUT + n] : 0.f;
    }
    __syncthreads();
    int nsl = t >> 6;
    us8 H8;
#pragma unroll
    for (int j = 0; j < 8; ++j) H8[j] = bf16h(sm.tile[q * 8 + j][nsl * 16 + c]);
    size_t dst = (((size_t)(e * 4 + nsl)) * 8 + kc) * 512 + l2 * 8;
    *(us8*)((ushort_t*)(ws + O_E3H) + dst) = H8;
  } else if (bk < 512) {   // ---- Xs: A-fragments of scaled x, 16 rows/block, hi+lo ----
    int msub = bk - 448;
    for (int i = t; i < 16 * 104; i += 256) {
      int b = i / 104, k = i - b * 104;
      float v = 0.f;
      if (k < DIN) { v = x[(size_t)(msub * 16 + b) * DIN + k]; if (k >= 100) v *= 100.f; }
      sm.xt[b][k] = v;
    }
    __syncthreads();
    int kc = t >> 6;
    int m = c;
    us8 H8, L8;
#pragma unroll
    for (int j = 0; j < 8; ++j) {
      int k = kc * 32 + q * 8 + j;
      float v = (k < 104) ? sm.xt[m][k] : 0.f;
      unsigned short h, lo; split_bf16(v, h, lo);
      H8[j] = h; L8[j] = lo;
    }
    size_t dst = ((size_t)msub * 4 + kc) * 512 + l2 * 8;
    *(us8*)((ushort_t*)(ws + O_XSH) + dst) = H8;
    *(us8*)((ushort_t*)(ws + O_XSL) + dst) = L8;
  } else {                 // ---- enc L1 (VALU): 16 rows/block ----
    float* slots1 = ws + O_SLOTS1;
    float* h1raw  = ws + O_H1RAW;
    int bkl = bk - 512;
    int r0 = bkl * 16;
    for (int i = t; i < 64 * DIN; i += 256) sm.e1.w1L[i] = w1[i];
    for (int i = t; i < 16 * 104; i += 256) {
      int r = i / 104, c2 = i - r * 104;
      float v = 0.f;
      if (c2 < DIN) { v = x[(size_t)(r0 + r) * DIN + c2]; if (c2 >= 100) v *= 100.f; }
      sm.e1.xr[r][c2] = v;
    }
    __syncthreads();
#pragma unroll
    for (int i = 0; i < 4; ++i) {
      int idx = t + i * 256;
      int r = idx >> 6, j = idx & 63;
      float acc = b1[j];
      for (int k = 0; k < DIN; ++k) acc = fmaf(sm.e1.xr[r][k], sm.e1.w1L[j * DIN + k], acc);
      sm.e1.hb[r][j] = acc;
      h1raw[(size_t)(r0 + r) * 64 + j] = acc;
    }
    __syncthreads();
    if (t < 64) {
      float s = 0.f, qq = 0.f;
      for (int r = 0; r < 16; ++r) { float v = sm.e1.hb[r][t]; s += v; qq += v * v; }
      slots1[bkl * 128 + t] = s;
      slots1[bkl * 128 + 64 + t] = qq;
    }
  }
}

// ================= K2: k_mega — 16 waves: enc2 -> gbar64 -> gate+gen1 -> gen2 -> gen3 =================
__global__ __launch_bounds__(1024) void k_mega(
    const float* __restrict__ gamma1, const float* __restrict__ beta1,
    const float* __restrict__ w2, const float* __restrict__ b2,
    const float* __restrict__ gamma2, const float* __restrict__ beta2,
    const float* __restrict__ gw1, const float* __restrict__ gb1,
    const float* __restrict__ gw2, const float* __restrict__ gb2,
    const float* __restrict__ gw3, const float* __restrict__ gb3,
    const float* __restrict__ eb1, const float* __restrict__ eb2,
    const float* __restrict__ eb3,
    float* __restrict__ ws, float* __restrict__ out) {
  __shared__ union {
    struct { float w2T[64 * 33]; float red[128]; float sc1[64], sh1[64];
             float h1b[16][64]; } enc2;
    struct { float gw1L[64 * 33]; float gw2L[64 * 65]; float gw3L[8 * 65];
             float gb1L[64], gb2L[64], gb3L[8];
             float red2[64], sc2[32], sh2[32];
             float lat[16][32]; float g1[16][64], g2[16][64]; } gate;
    struct { float hT[256][17]; float eb[2048]; } comb;
    struct { float p3s[8][16][64]; float eb3L[8][64]; } g3;
  } U;
  __shared__ float hb2s[16][32];     // enc L2 pre-BN output, persists P1 -> P2
  __shared__ us8 aHv[512], aLv[512]; // A-fragments [kc][l2], reused A1 -> A2
  __shared__ float bcL[16][8];       // persists P2 -> P4

  const int blk = blockIdx.x, t = threadIdx.x;
  const int wv = t >> 6, l = t & 63, c = l & 15, quad = l >> 4;
  const int R0 = blk * 16;
  unsigned* bar = (unsigned*)(ws + O_BAR);
  const ushort_t* XsH = (const ushort_t*)(ws + O_XSH);
  const ushort_t* XsL = (const ushort_t*)(ws + O_XSL);
  const ushort_t* E1H = (const ushort_t*)(ws + O_E1H);
  const ushort_t* E1L = (const ushort_t*)(ws + O_E1L);
  const ushort_t* E2H = (const ushort_t*)(ws + O_E2H);
  const ushort_t* E3H = (const ushort_t*)(ws + O_E3H);

  // early A-fragment loads (K1 output, plain cached)
  bf16x8 a1h[4], a1l[4];
#pragma unroll
  for (int kc = 0; kc < 4; ++kc) {
    a1h[kc] = *(const bf16x8*)(XsH + ((size_t)blk * 4 + kc) * 512 + l * 8);
    a1l[kc] = *(const bf16x8*)(XsL + ((size_t)blk * 4 + kc) * 512 + l * 8);
  }

  // ---------- P0: E-plane L2 prefetch (slice blk>>3; round-robin XCD assignment
  //            means each XCD's 8 blocks cover the full 2.25 MB) ----------
  {
    const int slice = blk >> 3;                 // 0..7, 73728 floats = 18432 float4
    const float4* src = (const float4*)(ws + O_E1H);
    float ka = 0.f;
#pragma unroll
    for (int i = 0; i < 18; ++i) {
      float4 v = src[(size_t)slice * 18432 + (size_t)i * 1024 + t];
      ka += v.x + v.y + v.z + v.w;
    }
    asm volatile("" :: "v"(ka));                // keep loads alive
  }

  // ---------- P1: enc2 for own 16 rows (hb2 stays in LDS; slots2 write-through) ----------
  {
    const float* slots1 = ws + O_SLOTS1;
    float* slots2 = ws + O_SLOTS2;
    const float* h1raw = ws + O_H1RAW;
    for (int i = t; i < 2048; i += 1024) { int j = i >> 6, k = i & 63; U.enc2.w2T[k * 33 + j] = w2[i]; }
    if (t < 128) {
      float s = 0.f;
      for (int b = 0; b < 64; ++b) s += slots1[b * 128 + t];
      U.enc2.red[t] = s;
    }
    __syncthreads();
    if (t < 64) {
      float mm = U.enc2.red[t] * (1.f / 1024.f);
      float v = U.enc2.red[64 + t] * (1.f / 1024.f) - mm * mm;
      float sc = gamma1[t] * rsqrtf(v + EPSBN);
      U.enc2.sc1[t] = sc; U.enc2.sh1[t] = beta1[t] - mm * sc;
    }
    __syncthreads();
    { int r = t >> 6, k = t & 63;              // 1024 = 16 x 64, one each
      U.enc2.h1b[r][k] = fmaxf(fmaf(h1raw[(size_t)(R0 + r) * 64 + k], U.enc2.sc1[k], U.enc2.sh1[k]), 0.f); }
    __syncthreads();
    if (t < 512) {
      int r = t >> 5, j = t & 31;              // 512 outputs = 16 x 32
      float acc = b2[j];
      for (int k = 0; k < 64; ++k) acc = fmaf(U.enc2.h1b[r][k], U.enc2.w2T[k * 33 + j], acc);
      hb2s[r][j] = acc;
    }
    __syncthreads();
    if (t < 32) {
      float s = 0.f, q = 0.f;
      for (int r = 0; r < 16; ++r) { float v = hb2s[r][t]; s += v; q += v * v; }
      stA(slots2 + blk * 64 + t, s);
      stA(slots2 + blk * 64 + 32 + t, q);
    }
  }
  gbar64(bar, blk);    // the ONLY grid sync

  // ---------- P2: gate (own rows, from LDS hb2s) + gen1+comb1 -> A1 frags ----------
  {
    const float* slots2 = ws + O_SLOTS2;
    for (int i = t; i < 2048; i += 1024) { int j = i >> 5, k = i & 31; U.gate.gw1L[j * 33 + k] = gw1[i]; }
    for (int i = t; i < 4096; i += 1024) { int j = i >> 6, k = i & 63; U.gate.gw2L[j * 65 + k] = gw2[i]; }
    if (t < 512) { int j = t >> 6, k = t & 63; U.gate.gw3L[j * 65 + k] = gw3[t]; }
    if (t < 64) { U.gate.gb1L[t] = gb1[t]; U.gate.gb2L[t] = gb2[t]; }
    if (t < 8) U.gate.gb3L[t] = gb3[t];
    if (t < 64) {
      float vvv[64];
#pragma unroll
      for (int b = 0; b < 64; ++b) vvv[b] = ldA(slots2 + b * 64 + t);
      float s = 0.f;
#pragma unroll
      for (int b = 0; b < 64; ++b) s += vvv[b];            // same order -> bit-identical
      U.gate.red2[t] = s;
    }
    __syncthreads();
    if (t < 32) {
      float mm = U.gate.red2[t] * (1.f / 1024.f);
      float v = U.gate.red2[32 + t] * (1.f / 1024.f) - mm * mm;
      float sc = gamma2[t] * rsqrtf(v + EPSBN);
      U.gate.sc2[t] = sc; U.gate.sh2[t] = beta2[t] - mm * sc;
    }
    __syncthreads();
    if (t < 512) { int r = t >> 5, cc = t & 31;
      U.gate.lat[r][cc] = fmaxf(fmaf(hb2s[r][cc], U.gate.sc2[cc], U.gate.sh2[cc]), 0.f); }
    __syncthreads();
    { int r = wv;                               // 16 waves = 16 rows, one each
      float a1 = U.gate.gb1L[l];
      for (int k = 0; k < 32; ++k) a1 = fmaf(U.gate.gw1L[l * 33 + k], U.gate.lat[r][k], a1);
      U.gate.g1[r][l] = eluf(a1);
    }
    __syncthreads();
    { int r = wv;
      float a2 = U.gate.gb2L[l];
      for (int k = 0; k < 64; ++k) a2 = fmaf(U.gate.gw2L[l * 65 + k], U.gate.g1[r][k], a2);
      U.gate.g2[r][l] = eluf(a2);
    }
    __syncthreads();
    { int r = wv;
      if (l < 8) {
        float a3 = U.gate.gb3L[l];
        for (int k = 0; k < 64; ++k) a3 = fmaf(U.gate.gw3L[l * 65 + k], U.gate.g2[r][k], a3);
        float mx = a3;
        mx = fmaxf(mx, __shfl_xor(mx, 1));
        mx = fmaxf(mx, __shfl_xor(mx, 2));
        mx = fmaxf(mx, __shfl_xor(mx, 4));
        float p = expf(a3 - mx);
        float sp = p;
        sp += __shfl_xor(sp, 1); sp += __shfl_xor(sp, 2); sp += __shfl_xor(sp, 4);
        bcL[r][l] = p / sp;
      }
    }
    __syncthreads();   // gate done; union reused below

    // gen1 + comb1: 16 waves x 1 ns each
    for (int i = t; i < 2048; i += 1024) U.comb.eb[i] = eb1[i];
    __syncthreads();
    {
      const int ns = wv;
      f32x4 blend = {};
#pragma unroll
      for (int e = 0; e < NE; ++e) {
        float bcv[4];
#pragma unroll
        for (int r = 0; r < 4; ++r) bcv[r] = bcL[quad * 4 + r][e];
        f32x4 acc = {};
#pragma unroll
        for (int kc = 0; kc < 4; ++kc) {
          size_t bo = (((size_t)(e * 16 + ns)) * 4 + kc) * 512 + l * 8;
          bf16x8 bh = *(const bf16x8*)(E1H + bo);
          bf16x8 bl = *(const bf16x8*)(E1L + bo);
          acc = MFMA(a1h[kc], bh, acc, 0, 0, 0);
          acc = MFMA(a1l[kc], bh, acc, 0, 0, 0);
          acc = MFMA(a1h[kc], bl, acc, 0, 0, 0);
        }
        float ebv = U.comb.eb[e * HH + ns * 16 + c];
#pragma unroll
        for (int r = 0; r < 4; ++r) blend[r] = fmaf(bcv[r], acc[r] + ebv, blend[r]);
      }
      int col = ns * 16 + c;
#pragma unroll
      for (int r = 0; r < 4; ++r) U.comb.hT[col][quad * 4 + r] = eluf(blend[r]);
    }
    __syncthreads();
    if (t < 512) {   // repack hT -> A1 fragments (hi+lo), t = kc*64 + l2
      int l2 = t & 63, row = l2 & 15, k0 = (t >> 6) * 32 + (l2 >> 4) * 8;
      us8 H, L;
#pragma unroll
      for (int j = 0; j < 8; ++j) {
        unsigned short h, lo; split_bf16(U.comb.hT[k0 + j][row], h, lo);
        H[j] = h; L[j] = lo;
      }
      aHv[t] = H; aLv[t] = L;
    }
    __syncthreads();
  }

  // ---------- P3: gen2 + comb2 -> A2 frags in LDS (A1 re-read from LDS per e) ----------
  {
    for (int i = t; i < 2048; i += 1024) U.comb.eb[i] = eb2[i];
    __syncthreads();
    {
      const int ns = wv;
      f32x4 blend = {};
#pragma unroll
      for (int e = 0; e < NE; ++e) {
        float bcv[4];
#pragma unroll
        for (int r = 0; r < 4; ++r) bcv[r] = bcL[quad * 4 + r][e];
        f32x4 acc = {};
#pragma unroll
        for (int kc = 0; kc < 8; ++kc) {
          size_t bo = (((size_t)(e * 16 + ns)) * 8 + kc) * 512 + l * 8;
          bf16x8 bh = *(const bf16x8*)(E2H + bo);
          bf16x8 ah = *(const bf16x8*)&aHv[kc * 64 + l];
          bf16x8 al = *(const bf16x8*)&aLv[kc * 64 + l];
          acc = MFMA(ah, bh, acc, 0, 0, 0);
          acc = MFMA(al, bh, acc, 0, 0, 0);
        }
        float ebv = U.comb.eb[e * HH + ns * 16 + c];
#pragma unroll
        for (int r = 0; r < 4; ++r) blend[r] = fmaf(bcv[r], acc[r] + ebv, blend[r]);
      }
      int col = ns * 16 + c;
#pragma unroll
      for (int r = 0; r < 4; ++r) U.comb.hT[col][quad * 4 + r] = eluf(blend[r]);
    }
    __syncthreads();
    if (t < 512) {   // repack hT -> A2 fragments (overwrites A1; all consumers synced)
      int l2 = t & 63, row = l2 & 15, k0 = (t >> 6) * 32 + (l2 >> 4) * 8;
      us8 H, L;
#pragma unroll
      for (int j = 0; j < 8; ++j) {
        unsigned short h, lo; split_bf16(U.comb.hT[k0 + j][row], h, lo);
        H[j] = h; L[j] = lo;
      }
      aHv[t] = H; aLv[t] = L;
    }
    __syncthreads();
  }

  // ---------- P4: gen3 (waves 0-7 = experts) + 1024-wide reduce -> out ----------
  {
    if (t < 512) { int e = t >> 6, n = t & 63; U.g3.eb3L[e][n] = (n < DOUT) ? eb3[e * DOUT + n] : 0.f; }
    if (wv < 8) {
      const int e = wv;
      f32x4 acc[4] = {};
#pragma unroll
      for (int kc = 0; kc < 8; ++kc) {
        bf16x8 ah = *(const bf16x8*)&aHv[kc * 64 + l];
        bf16x8 al = *(const bf16x8*)&aLv[kc * 64 + l];
#pragma unroll
        for (int nsi = 0; nsi < 4; ++nsi) {
          size_t bo = (((size_t)(e * 4 + nsi)) * 8 + kc) * 512 + l * 8;
          bf16x8 bh = *(const bf16x8*)(E3H + bo);
          acc[nsi] = MFMA(ah, bh, acc[nsi], 0, 0, 0);
          acc[nsi] = MFMA(al, bh, acc[nsi], 0, 0, 0);
        }
      }
#pragma unroll
      for (int nsi = 0; nsi < 4; ++nsi)
#pragma unroll
        for (int r = 0; r < 4; ++r)
          U.g3.p3s[e][quad * 4 + r][nsi * 16 + c] = acc[nsi][r];
    }
    __syncthreads();
    {
      int row = t >> 6, col = t & 63;          // 1024 outputs, one each
      float s = 0.f;
#pragma unroll
      for (int e2 = 0; e2 < 8; ++e2)
        s = fmaf(bcL[row][e2], U.g3.p3s[e2][row][col] + U.g3.eb3L[e2][col], s);
      if (col < DOUT) out[(size_t)(R0 + row) * DOUT + col] = s;
    }
  }
}

extern "C" void kernel_launch(void* const* d_in, const int* in_sizes, int n_in,
                              void* d_out, int out_size, void* d_ws, size_t ws_size,
                              hipStream_t stream) {
  const float* x      = (const float*)d_in[0];
  const float* w1     = (const float*)d_in[1];
  const float* b1     = (const float*)d_in[2];
  const float* gamma1 = (const float*)d_in[3];
  const float* beta1  = (const float*)d_in[4];
  const float* w2     = (const float*)d_in[5];
  const float* b2     = (const float*)d_in[6];
  const float* gamma2 = (const float*)d_in[7];
  const float* beta2  = (const float*)d_in[8];
  const float* gw1    = (const float*)d_in[9];
  const float* gb1    = (const float*)d_in[10];
  const float* gw2    = (const float*)d_in[11];
  const float* gb2    = (const float*)d_in[12];
  const float* gw3    = (const float*)d_in[13];
  const float* gb3    = (const float*)d_in[14];
  const float* ew1    = (const float*)d_in[15];
  const float* eb1    = (const float*)d_in[16];
  const float* ew2    = (const float*)d_in[17];
  const float* eb2    = (const float*)d_in[18];
  const float* ew3    = (const float*)d_in[19];
  const float* eb3    = (const float*)d_in[20];
  float* wsf  = (float*)d_ws;
  float* outp = (float*)d_out;

  k_prep_enc1<<<576, 256, 0, stream>>>(x, w1, b1, ew1, ew2, ew3, wsf);
  k_mega<<<64, 1024, 0, stream>>>(gamma1, beta1, w2, b2, gamma2, beta2,
                                  gw1, gb1, gw2, gb2, gw3, gb3,
                                  eb1, eb2, eb3, wsf, outp);
}